// Round 1
// baseline (10388.721 us; speedup 1.0000x reference)
//
#include <hip/hip_runtime.h>
#include <math.h>

#define BB 8
#define SS 2048
#define HH 8
#define DM 512
#define DK 64

// ---------------- Kernel P: per-head projection GEMM ----------------
// Y[b,h,s,n] = sum_d X[b,s,d] * W[h,d,n] + bias[h,n]
// grid: (SS/64, BB*HH), block 256
__global__ __launch_bounds__(256) void proj_kernel(const float* __restrict__ X,
                                                   const float* __restrict__ W,
                                                   const float* __restrict__ bias,
                                                   float* __restrict__ Y) {
    __shared__ float Xs[64][32];
    __shared__ float Ws[32][64];
    const int bh = blockIdx.y;
    const int b = bh / HH, h = bh % HH;
    const int s0 = blockIdx.x * 64;
    const int t = threadIdx.x;
    const int n = t & 63;
    const int qr = t >> 6;
    float acc[16];
#pragma unroll
    for (int i = 0; i < 16; ++i) acc[i] = 0.f;
    const float* Xb = X + ((size_t)b * SS + s0) * DM;
    const float* Wh = W + (size_t)h * DM * DK;
    for (int k0 = 0; k0 < DM; k0 += 32) {
        // X tile 64x32 (512 float4, 2/thread) — linear LDS offsets, conflict-free
#pragma unroll
        for (int it = 0; it < 2; ++it) {
            int j = t + 256 * it;
            int row = j >> 3, c4 = (j & 7) * 4;
            *(float4*)&Xs[row][c4] = *(const float4*)(Xb + (size_t)row * DM + k0 + c4);
        }
        // W tile 32x64
#pragma unroll
        for (int it = 0; it < 2; ++it) {
            int j = t + 256 * it;
            int row = j >> 4, c4 = (j & 15) * 4;
            *(float4*)&Ws[row][c4] = *(const float4*)(Wh + (size_t)(k0 + row) * DK + c4);
        }
        __syncthreads();
#pragma unroll
        for (int kk = 0; kk < 32; ++kk) {
            float wv = Ws[kk][n];
#pragma unroll
            for (int i = 0; i < 16; ++i)
                acc[i] = fmaf(Xs[qr + 4 * i][kk], wv, acc[i]);
        }
        __syncthreads();
    }
    const float bv = bias[h * DK + n];
    float* Yb = Y + (((size_t)b * HH + h) * SS + s0) * DK;
#pragma unroll
    for (int i = 0; i < 16; ++i)
        Yb[(size_t)(qr + 4 * i) * DK + n] = acc[i] + bv;
}

// ---------------- Kernel S: per-key softmax stats over the QUERY axis ----------------
// For each (b,h,k): m[k] = max_q s(q,k), Z[k] = sum_q exp(s(q,k)-m[k]), s = qh.kh/8
// grid: (SS/64 k-tiles, BB*HH), block 256
__global__ __launch_bounds__(256) void stats_kernel(const float* __restrict__ qh,
                                                    const float* __restrict__ kh,
                                                    float* __restrict__ mOut,
                                                    float* __restrict__ zOut) {
    __shared__ float Ks[64][65];   // pad 65: read Ks[kc][d], kc per-lane -> 2-way (free)
    __shared__ float Qs[64][64];   // broadcast reads, no pad needed
    __shared__ float redM[4][64];
    __shared__ float redZ[4][64];
    const int bh = blockIdx.y;
    const int k0 = blockIdx.x * 64;
    const int t = threadIdx.x;
    const int kc = t & 63;
    const int qr = t >> 6;
    const float* Kb = kh + ((size_t)bh * SS + k0) * DK;
    const float* Qb = qh + (size_t)bh * SS * DK;
    // load K tile 64x64 (scalar LDS stores due to pad-65; 2-way write conflicts = free)
#pragma unroll
    for (int it = 0; it < 4; ++it) {
        int j = t + 256 * it;
        int row = j >> 4, c4 = (j & 15) * 4;
        const float4 v = *(const float4*)(Kb + (size_t)row * DK + c4);
        Ks[row][c4 + 0] = v.x; Ks[row][c4 + 1] = v.y;
        Ks[row][c4 + 2] = v.z; Ks[row][c4 + 3] = v.w;
    }
    float mt = -INFINITY, zt = 0.f;
    for (int q0 = 0; q0 < SS; q0 += 64) {
        __syncthreads();   // protect Qs from previous use (and K tile on first iter)
#pragma unroll
        for (int it = 0; it < 4; ++it) {
            int j = t + 256 * it;
            int row = j >> 4, c4 = (j & 15) * 4;
            *(float4*)&Qs[row][c4] = *(const float4*)(Qb + (size_t)(q0 + row) * DK + c4);
        }
        __syncthreads();
#pragma unroll
        for (int i = 0; i < 16; ++i) {
            const int qq = qr + 4 * i;
            float s = 0.f;
#pragma unroll
            for (int d = 0; d < 64; ++d)
                s = fmaf(Qs[qq][d], Ks[kc][d], s);
            s *= 0.125f;
            float nm = fmaxf(mt, s);
            zt = zt * __expf(mt - nm) + __expf(s - nm);
            mt = nm;
        }
    }
    redM[qr][kc] = mt;
    redZ[qr][kc] = zt;
    __syncthreads();
    if (qr == 0) {
        float m0 = redM[0][kc], m1 = redM[1][kc], m2 = redM[2][kc], m3 = redM[3][kc];
        float mm = fmaxf(fmaxf(m0, m1), fmaxf(m2, m3));
        float z = redZ[0][kc] * __expf(m0 - mm) + redZ[1][kc] * __expf(m1 - mm)
                + redZ[2][kc] * __expf(m2 - mm) + redZ[3][kc] * __expf(m3 - mm);
        mOut[(size_t)bh * SS + k0 + kc] = mm;
        zOut[(size_t)bh * SS + k0 + kc] = z;
    }
}

// ---------------- Kernel C: context = (exp(s - m[k]) / Z[k]) @ vh ----------------
// grid: (SS/64 q-tiles, BB*HH), block 256
__global__ __launch_bounds__(256) void ctx_kernel(const float* __restrict__ qh,
                                                  const float* __restrict__ kh,
                                                  const float* __restrict__ vh,
                                                  const float* __restrict__ mIn,
                                                  const float* __restrict__ zIn,
                                                  float* __restrict__ ctx) {
    __shared__ float Qs[64][64];   // broadcast reads
    __shared__ float Ks[64][65];   // per-lane row reads -> pad
    __shared__ float Vs[64][64];   // read Vs[k][lane]: stride-1 -> 2-way free
    __shared__ float Ps[64][64];   // w tile [q][k]; broadcast reads
    const int bh = blockIdx.y;
    const int q0 = blockIdx.x * 64;
    const int t = threadIdx.x;
    const int lane = t & 63;       // k-col in score phase, v-col in accum phase
    const int qr = t >> 6;
    const float* Qb = qh + ((size_t)bh * SS + q0) * DK;
    const float* Kb = kh + (size_t)bh * SS * DK;
    const float* Vb = vh + (size_t)bh * SS * DK;
    // load Q tile once
#pragma unroll
    for (int it = 0; it < 4; ++it) {
        int j = t + 256 * it;
        int row = j >> 4, c4 = (j & 15) * 4;
        *(float4*)&Qs[row][c4] = *(const float4*)(Qb + (size_t)row * DK + c4);
    }
    float acc[16];
#pragma unroll
    for (int i = 0; i < 16; ++i) acc[i] = 0.f;
    for (int k0 = 0; k0 < SS; k0 += 64) {
        __syncthreads();   // protect prior-iter Ks/Vs/Ps use (and Qs load on iter 0)
#pragma unroll
        for (int it = 0; it < 4; ++it) {
            int j = t + 256 * it;
            int row = j >> 4, c4 = (j & 15) * 4;
            const float4 kv = *(const float4*)(Kb + (size_t)(k0 + row) * DK + c4);
            Ks[row][c4 + 0] = kv.x; Ks[row][c4 + 1] = kv.y;
            Ks[row][c4 + 2] = kv.z; Ks[row][c4 + 3] = kv.w;
            *(float4*)&Vs[row][c4] = *(const float4*)(Vb + (size_t)(k0 + row) * DK + c4);
        }
        const float mk = mIn[(size_t)bh * SS + k0 + lane];
        const float invz = 1.f / zIn[(size_t)bh * SS + k0 + lane];
        __syncthreads();
        // scores -> weights into Ps
#pragma unroll
        for (int i = 0; i < 16; ++i) {
            const int qq = qr + 4 * i;
            float s = 0.f;
#pragma unroll
            for (int d = 0; d < 64; ++d)
                s = fmaf(Qs[qq][d], Ks[lane][d], s);
            s *= 0.125f;
            Ps[qq][lane] = __expf(s - mk) * invz;
        }
        __syncthreads();
        // accumulate ctx += Ps @ Vs
#pragma unroll
        for (int k = 0; k < 64; ++k) {
            const float vv = Vs[k][lane];
#pragma unroll
            for (int i = 0; i < 16; ++i)
                acc[i] = fmaf(Ps[qr + 4 * i][k], vv, acc[i]);
        }
    }
    float* Cb = ctx + ((size_t)bh * SS + q0) * DK;
#pragma unroll
    for (int i = 0; i < 16; ++i)
        Cb[(size_t)(qr + 4 * i) * DK + lane] = acc[i];
}

// ---------------- Kernel O: output projection ----------------
// out[r, j] = sum_i concat[r, i] * Wo[i, j] + bo[j], concat[b,s,h*64+v] = ctx[b,h,s,v]
// grid: (BB*SS/64, DM/64), block 256
__global__ __launch_bounds__(256) void out_kernel(const float* __restrict__ ctx,
                                                  const float* __restrict__ Wo,
                                                  const float* __restrict__ bo,
                                                  float* __restrict__ out) {
    __shared__ float Xs[64][32];
    __shared__ float Ws[32][64];
    const int r0 = blockIdx.x * 64;
    const int j0 = blockIdx.y * 64;
    const int t = threadIdx.x;
    const int n = t & 63;
    const int qr = t >> 6;
    float acc[16];
#pragma unroll
    for (int i = 0; i < 16; ++i) acc[i] = 0.f;
    for (int k0 = 0; k0 < DM; k0 += 32) {
#pragma unroll
        for (int it = 0; it < 2; ++it) {
            int j = t + 256 * it;
            int row = j >> 3, c4 = (j & 7) * 4;
            int gr = r0 + row;
            int b = gr >> 11;        // / SS
            int s = gr & (SS - 1);
            int i = k0 + c4;         // h = i>>6, v = i&63 (32-chunks never cross heads)
            *(float4*)&Xs[row][c4] =
                *(const float4*)(ctx + (((size_t)b * HH + (i >> 6)) * SS + s) * DK + (i & 63));
        }
#pragma unroll
        for (int it = 0; it < 2; ++it) {
            int j = t + 256 * it;
            int row = j >> 4, c4 = (j & 15) * 4;
            *(float4*)&Ws[row][c4] = *(const float4*)(Wo + (size_t)(k0 + row) * DM + j0 + c4);
        }
        __syncthreads();
#pragma unroll
        for (int kk = 0; kk < 32; ++kk) {
            float wv = Ws[kk][n];
#pragma unroll
            for (int i2 = 0; i2 < 16; ++i2)
                acc[i2] = fmaf(Xs[qr + 4 * i2][kk], wv, acc[i2]);
        }
        __syncthreads();
    }
    const float bv = bo[j0 + n];
#pragma unroll
    for (int i2 = 0; i2 < 16; ++i2)
        out[(size_t)(r0 + qr + 4 * i2) * DM + j0 + n] = acc[i2] + bv;
}

extern "C" void kernel_launch(void* const* d_in, const int* in_sizes, int n_in,
                              void* d_out, int out_size, void* d_ws, size_t ws_size,
                              hipStream_t stream) {
    const float* q  = (const float*)d_in[0];
    const float* k  = (const float*)d_in[1];
    const float* v  = (const float*)d_in[2];
    const float* Wq = (const float*)d_in[3];
    const float* bq = (const float*)d_in[4];
    const float* Wk = (const float*)d_in[5];
    const float* bk = (const float*)d_in[6];
    const float* Wv = (const float*)d_in[7];
    const float* bv = (const float*)d_in[8];
    const float* Wo = (const float*)d_in[9];
    const float* bo = (const float*)d_in[10];
    float* out = (float*)d_out;

    float* ws = (float*)d_ws;
    const size_t NH  = (size_t)BB * HH * SS * DK;   // 8,388,608
    const size_t BHS = (size_t)BB * HH * SS;        // 131,072
    float* qh  = ws;
    float* kh  = ws + NH;
    float* vhp = ws + 2 * NH;
    float* mb  = ws + 3 * NH;
    float* zb  = mb + BHS;
    float* ctx = zb + BHS;

    dim3 blk(256);
    dim3 gP(SS / 64, BB * HH);
    proj_kernel<<<gP, blk, 0, stream>>>(q, Wq, bq, qh);
    proj_kernel<<<gP, blk, 0, stream>>>(k, Wk, bk, kh);
    proj_kernel<<<gP, blk, 0, stream>>>(v, Wv, bv, vhp);
    stats_kernel<<<dim3(SS / 64, BB * HH), blk, 0, stream>>>(qh, kh, mb, zb);
    ctx_kernel<<<dim3(SS / 64, BB * HH), blk, 0, stream>>>(qh, kh, vhp, mb, zb, ctx);
    out_kernel<<<dim3(BB * SS / 64, DM / 64), blk, 0, stream>>>(ctx, Wo, bo, out);
}

// Round 2
// 1221.644 us; speedup vs baseline: 8.5039x; 8.5039x over previous
//
#include <hip/hip_runtime.h>
#include <hip/hip_bf16.h>
#include <math.h>

#define BB 8
#define SS 2048
#define HH 8
#define DM 512
#define DK 64

typedef short bf16x8 __attribute__((ext_vector_type(8)));
typedef float f32x4 __attribute__((ext_vector_type(4)));

static __device__ __forceinline__ short f2bf(float f) {
    union { __hip_bfloat16 h; short s; } u;
    u.h = __float2bfloat16(f);
    return u.s;
}

// swizzled LDS helpers: tiles are [rows][64] bf16 (128B rows), swizzle = XOR of
// 16B-slot index with (row&7)  ->  short-index ^= ((row&7)<<3)
static __device__ __forceinline__ bf16x8 fragRow(const short* lds, int row, int cshort) {
    return *(const bf16x8*)(lds + row * 64 + (cshort ^ ((row & 7) << 3)));
}

// stage a [64][64] bf16 tile from row-major global (gstride in shorts), swizzled
static __device__ __forceinline__ void stage64(short* lds, const short* g, int gstride, int t) {
#pragma unroll
    for (int p = 0; p < 2; ++p) {
        int idx = t + p * 256;          // 16B chunk id
        int row = idx >> 3;
        int cs  = (idx & 7) << 3;       // short col
        bf16x8 v = *(const bf16x8*)(g + (size_t)row * gstride + cs);
        *(bf16x8*)(lds + row * 64 + (cs ^ ((row & 7) << 3))) = v;
    }
}

// ---------------- projection GEMM (fp32 compute), bf16 row-major output ----------------
__global__ __launch_bounds__(256) void proj_bf(const float* __restrict__ X,
                                               const float* __restrict__ W,
                                               const float* __restrict__ bias,
                                               short* __restrict__ Y, float scale) {
    __shared__ float Xs[64][32];
    __shared__ float Ws[32][64];
    const int bh = blockIdx.y;
    const int b = bh / HH, h = bh % HH;
    const int s0 = blockIdx.x * 64;
    const int t = threadIdx.x;
    const int n = t & 63;
    const int qr = t >> 6;
    float acc[16];
#pragma unroll
    for (int i = 0; i < 16; ++i) acc[i] = 0.f;
    const float* Xb = X + ((size_t)b * SS + s0) * DM;
    const float* Wh = W + (size_t)h * DM * DK;
    for (int k0 = 0; k0 < DM; k0 += 32) {
#pragma unroll
        for (int it = 0; it < 2; ++it) {
            int j = t + 256 * it;
            int row = j >> 3, c4 = (j & 7) * 4;
            *(float4*)&Xs[row][c4] = *(const float4*)(Xb + (size_t)row * DM + k0 + c4);
        }
#pragma unroll
        for (int it = 0; it < 2; ++it) {
            int j = t + 256 * it;
            int row = j >> 4, c4 = (j & 15) * 4;
            *(float4*)&Ws[row][c4] = *(const float4*)(Wh + (size_t)(k0 + row) * DK + c4);
        }
        __syncthreads();
#pragma unroll
        for (int kk = 0; kk < 32; ++kk) {
            float wv = Ws[kk][n];
#pragma unroll
            for (int i = 0; i < 16; ++i)
                acc[i] = fmaf(Xs[qr + 4 * i][kk], wv, acc[i]);
        }
        __syncthreads();
    }
    const float bv = bias[h * DK + n];
    short* Yb = Y + (((size_t)b * HH + h) * SS + s0) * DK;
#pragma unroll
    for (int i = 0; i < 16; ++i)
        Yb[(size_t)(qr + 4 * i) * DK + n] = f2bf((acc[i] + bv) * scale);
}

// ---------------- V projection, bf16 TRANSPOSED output [b,h,64,2048] ----------------
__global__ __launch_bounds__(256) void proj_vT(const float* __restrict__ X,
                                               const float* __restrict__ W,
                                               const float* __restrict__ bias,
                                               short* __restrict__ YT) {
    __shared__ float Xs[64][32];
    __shared__ float Ws[32][64];
    __shared__ float Ts[64][65];
    const int bh = blockIdx.y;
    const int b = bh / HH, h = bh % HH;
    const int s0 = blockIdx.x * 64;
    const int t = threadIdx.x;
    const int n = t & 63;
    const int qr = t >> 6;
    float acc[16];
#pragma unroll
    for (int i = 0; i < 16; ++i) acc[i] = 0.f;
    const float* Xb = X + ((size_t)b * SS + s0) * DM;
    const float* Wh = W + (size_t)h * DM * DK;
    for (int k0 = 0; k0 < DM; k0 += 32) {
#pragma unroll
        for (int it = 0; it < 2; ++it) {
            int j = t + 256 * it;
            int row = j >> 3, c4 = (j & 7) * 4;
            *(float4*)&Xs[row][c4] = *(const float4*)(Xb + (size_t)row * DM + k0 + c4);
        }
#pragma unroll
        for (int it = 0; it < 2; ++it) {
            int j = t + 256 * it;
            int row = j >> 4, c4 = (j & 15) * 4;
            *(float4*)&Ws[row][c4] = *(const float4*)(Wh + (size_t)(k0 + row) * DK + c4);
        }
        __syncthreads();
#pragma unroll
        for (int kk = 0; kk < 32; ++kk) {
            float wv = Ws[kk][n];
#pragma unroll
            for (int i = 0; i < 16; ++i)
                acc[i] = fmaf(Xs[qr + 4 * i][kk], wv, acc[i]);
        }
        __syncthreads();
    }
    const float bv = bias[h * DK + n];
#pragma unroll
    for (int i = 0; i < 16; ++i)
        Ts[n][qr + 4 * i] = acc[i] + bv;     // Ts[v][s_local]
    __syncthreads();
    const int v = t >> 2, part = t & 3;
    short* Yb = YT + (((size_t)b * HH + h) * DK + v) * SS + s0 + part * 16;
    bf16x8 o0, o1;
#pragma unroll
    for (int j = 0; j < 8; ++j) o0[j] = f2bf(Ts[v][part * 16 + j]);
#pragma unroll
    for (int j = 0; j < 8; ++j) o1[j] = f2bf(Ts[v][part * 16 + 8 + j]);
    *(bf16x8*)(Yb) = o0;
    *(bf16x8*)(Yb + 8) = o1;
}

// ---------------- stats: per-key m / 1/Z over the QUERY axis (MFMA) ----------------
// grid: (SS/64 k-tiles, BB*HH), block 256 (4 waves; wave w owns k-cols 16w..16w+15)
__global__ __launch_bounds__(256) void stats_mfma(const short* __restrict__ qs,
                                                  const short* __restrict__ kh,
                                                  float* __restrict__ mOut,
                                                  float* __restrict__ izOut) {
    __shared__ short Ks[64 * 64];
    __shared__ short Qs[64 * 64];
    const int bh = blockIdx.y;
    const int k0 = blockIdx.x * 64;
    const int t = threadIdx.x;
    const int l = t & 63;
    const int w = t >> 6;
    const int lr = l & 15;
    const int g = l >> 4;
    const short* Qb = qs + (size_t)bh * SS * DK;
    const short* Kb = kh + ((size_t)bh * SS + k0) * DK;

    stage64(Ks, Kb, DK, t);
    __syncthreads();
    // B-operand (K) frags for this wave's 16 k-cols, hoisted: elems d = 32c+8g+e
    bf16x8 bk0 = fragRow(Ks, 16 * w + lr, 8 * g);
    bf16x8 bk1 = fragRow(Ks, 16 * w + lr, 32 + 8 * g);

    float mt = -INFINITY, zt = 0.f;
    for (int q0 = 0; q0 < SS; q0 += 64) {
        __syncthreads();
        stage64(Qs, Qb + (size_t)q0 * DK, DK, t);
        __syncthreads();
#pragma unroll
        for (int qf = 0; qf < 4; ++qf) {
            bf16x8 aq0 = fragRow(Qs, 16 * qf + lr, 8 * g);
            bf16x8 aq1 = fragRow(Qs, 16 * qf + lr, 32 + 8 * g);
            f32x4 s = {0.f, 0.f, 0.f, 0.f};
            s = __builtin_amdgcn_mfma_f32_16x16x32_bf16(aq0, bk0, s, 0, 0, 0);
            s = __builtin_amdgcn_mfma_f32_16x16x32_bf16(aq1, bk1, s, 0, 0, 0);
#pragma unroll
            for (int r = 0; r < 4; ++r) {
                float sv = s[r];
                float nm = fmaxf(mt, sv);
                zt = zt * __expf(mt - nm) + __expf(sv - nm);
                mt = nm;
            }
        }
    }
    // merge across the 4 lane-groups (same k, different q subsets)
#pragma unroll
    for (int off = 16; off <= 32; off <<= 1) {
        float om = __shfl_xor(mt, off);
        float oz = __shfl_xor(zt, off);
        float nm = fmaxf(mt, om);
        zt = zt * __expf(mt - nm) + oz * __expf(om - nm);
        mt = nm;
    }
    if (l < 16) {
        mOut[(size_t)bh * SS + k0 + 16 * w + l] = mt;
        izOut[(size_t)bh * SS + k0 + 16 * w + l] = 1.f / zt;
    }
}

// ---------------- ctx: P = exp(S-m[k])*invz[k]; ctx = P @ V  (MFMA, swapped QK^T) ----------------
// grid: (SS/128 q-tiles, BB*HH), block 256 (4 waves; wave w owns q-rows 32w..32w+31)
__global__ __launch_bounds__(256) void ctx_mfma(const short* __restrict__ qs,
                                                const short* __restrict__ kh,
                                                const short* __restrict__ vT,
                                                const float* __restrict__ mArr,
                                                const float* __restrict__ izArr,
                                                float* __restrict__ ctx) {
    __shared__ short Qs[128 * 64];
    __shared__ short Ks[64 * 64];
    __shared__ short Vs[64 * 64];
    const int bh = blockIdx.y;
    const int q0 = blockIdx.x * 128;
    const int t = threadIdx.x;
    const int l = t & 63;
    const int w = t >> 6;
    const int lr = l & 15;
    const int g = l >> 4;
    const short* Qb = qs + ((size_t)bh * SS + q0) * DK;
    const short* Kb = kh + (size_t)bh * SS * DK;
    const short* Vb = vT + (size_t)bh * DK * SS;
    const float* mB = mArr + (size_t)bh * SS;
    const float* zB = izArr + (size_t)bh * SS;

    // stage Q tile (128x64) once
#pragma unroll
    for (int p = 0; p < 4; ++p) {
        int idx = t + p * 256;
        int row = idx >> 3;
        int cs = (idx & 7) << 3;
        *(bf16x8*)(Qs + row * 64 + (cs ^ ((row & 7) << 3))) = *(const bf16x8*)(Qb + (size_t)row * DK + cs);
    }
    __syncthreads();
    // hoist Q as B-operand frags: col q = 32w + 16qf + lr, elems d = 32c+8g+e
    bf16x8 qfr[2][2];
#pragma unroll
    for (int qf = 0; qf < 2; ++qf)
#pragma unroll
        for (int c = 0; c < 2; ++c)
            qfr[qf][c] = fragRow(Qs, 32 * w + 16 * qf + lr, 32 * c + 8 * g);

    f32x4 acc[2][4];  // [qf][vf]
#pragma unroll
    for (int a = 0; a < 2; ++a)
#pragma unroll
        for (int b2 = 0; b2 < 4; ++b2) acc[a][b2] = (f32x4){0.f, 0.f, 0.f, 0.f};

    for (int k0 = 0; k0 < SS; k0 += 64) {
        __syncthreads();
        stage64(Ks, Kb + (size_t)k0 * DK, DK, t);
        stage64(Vs, Vb + k0, SS, t);
        __syncthreads();

        // S phase (swapped: mfma(K,Q) -> D[k][q], lane col = q)
        float pw[2][4][4];  // [qf][kf][r]; k = k0 + 16kf + 4g + r
#pragma unroll
        for (int kf = 0; kf < 4; ++kf) {
            bf16x8 ak0 = fragRow(Ks, 16 * kf + lr, 8 * g);
            bf16x8 ak1 = fragRow(Ks, 16 * kf + lr, 32 + 8 * g);
            f32x4 m4 = *(const f32x4*)(mB + k0 + 16 * kf + 4 * g);
            f32x4 z4 = *(const f32x4*)(zB + k0 + 16 * kf + 4 * g);
#pragma unroll
            for (int qf = 0; qf < 2; ++qf) {
                f32x4 s = {0.f, 0.f, 0.f, 0.f};
                s = __builtin_amdgcn_mfma_f32_16x16x32_bf16(ak0, qfr[qf][0], s, 0, 0, 0);
                s = __builtin_amdgcn_mfma_f32_16x16x32_bf16(ak1, qfr[qf][1], s, 0, 0, 0);
#pragma unroll
                for (int r = 0; r < 4; ++r)
                    pw[qf][kf][r] = __expf(s[r] - m4[r]) * z4[r];
            }
        }
        // pack P rows (lane-local in q) into bf16 A-frags; k-mapping e -> 32c + 16(e>>2) + 4g + (e&3)
        bf16x8 pa[2][2];  // [qf][c]
#pragma unroll
        for (int qf = 0; qf < 2; ++qf)
#pragma unroll
            for (int c = 0; c < 2; ++c) {
#pragma unroll
                for (int e = 0; e < 4; ++e) {
                    pa[qf][c][e]     = f2bf(pw[qf][2 * c][e]);
                    pa[qf][c][4 + e] = f2bf(pw[qf][2 * c + 1][e]);
                }
            }
        // PV: B = V^T rows (col v = 16vf + lr), same custom k-mapping
#pragma unroll
        for (int vf = 0; vf < 4; ++vf) {
            const int rowv = 16 * vf + lr;
            const int swz = (rowv & 7) << 3;
#pragma unroll
            for (int c = 0; c < 2; ++c) {
                ushort4 lo = *(const ushort4*)(Vs + rowv * 64 + ((32 * c + 4 * g) ^ swz));
                ushort4 hi = *(const ushort4*)(Vs + rowv * 64 + ((32 * c + 16 + 4 * g) ^ swz));
                bf16x8 bv;
                bv[0] = lo.x; bv[1] = lo.y; bv[2] = lo.z; bv[3] = lo.w;
                bv[4] = hi.x; bv[5] = hi.y; bv[6] = hi.z; bv[7] = hi.w;
#pragma unroll
                for (int qf = 0; qf < 2; ++qf)
                    acc[qf][vf] = __builtin_amdgcn_mfma_f32_16x16x32_bf16(pa[qf][c], bv, acc[qf][vf], 0, 0, 0);
            }
        }
    }
    float* Cb = ctx + ((size_t)bh * SS + q0) * DK;
#pragma unroll
    for (int qf = 0; qf < 2; ++qf)
#pragma unroll
        for (int vf = 0; vf < 4; ++vf)
#pragma unroll
            for (int r = 0; r < 4; ++r)
                Cb[(size_t)(32 * w + 16 * qf + 4 * g + r) * DK + 16 * vf + lr] = acc[qf][vf][r];
}

// ---------------- output projection (fp32) ----------------
__global__ __launch_bounds__(256) void out_kernel(const float* __restrict__ ctx,
                                                  const float* __restrict__ Wo,
                                                  const float* __restrict__ bo,
                                                  float* __restrict__ out) {
    __shared__ float Xs[64][32];
    __shared__ float Ws[32][64];
    const int r0 = blockIdx.x * 64;
    const int j0 = blockIdx.y * 64;
    const int t = threadIdx.x;
    const int n = t & 63;
    const int qr = t >> 6;
    float acc[16];
#pragma unroll
    for (int i = 0; i < 16; ++i) acc[i] = 0.f;
    for (int k0 = 0; k0 < DM; k0 += 32) {
#pragma unroll
        for (int it = 0; it < 2; ++it) {
            int j = t + 256 * it;
            int row = j >> 3, c4 = (j & 7) * 4;
            int gr = r0 + row;
            int b = gr >> 11;
            int s = gr & (SS - 1);
            int i = k0 + c4;
            *(float4*)&Xs[row][c4] =
                *(const float4*)(ctx + (((size_t)b * HH + (i >> 6)) * SS + s) * DK + (i & 63));
        }
#pragma unroll
        for (int it = 0; it < 2; ++it) {
            int j = t + 256 * it;
            int row = j >> 4, c4 = (j & 15) * 4;
            *(float4*)&Ws[row][c4] = *(const float4*)(Wo + (size_t)(k0 + row) * DM + j0 + c4);
        }
        __syncthreads();
#pragma unroll
        for (int kk = 0; kk < 32; ++kk) {
            float wv = Ws[kk][n];
#pragma unroll
            for (int i2 = 0; i2 < 16; ++i2)
                acc[i2] = fmaf(Xs[qr + 4 * i2][kk], wv, acc[i2]);
        }
        __syncthreads();
    }
    const float bv = bo[j0 + n];
#pragma unroll
    for (int i2 = 0; i2 < 16; ++i2)
        out[(size_t)(r0 + qr + 4 * i2) * DM + j0 + n] = acc[i2] + bv;
}

extern "C" void kernel_launch(void* const* d_in, const int* in_sizes, int n_in,
                              void* d_out, int out_size, void* d_ws, size_t ws_size,
                              hipStream_t stream) {
    const float* q  = (const float*)d_in[0];
    const float* k  = (const float*)d_in[1];
    const float* v  = (const float*)d_in[2];
    const float* Wq = (const float*)d_in[3];
    const float* bq = (const float*)d_in[4];
    const float* Wk = (const float*)d_in[5];
    const float* bk = (const float*)d_in[6];
    const float* Wv = (const float*)d_in[7];
    const float* bv = (const float*)d_in[8];
    const float* Wo = (const float*)d_in[9];
    const float* bo = (const float*)d_in[10];
    float* out = (float*)d_out;

    char* w8 = (char*)d_ws;
    const size_t NH = (size_t)BB * HH * SS * DK;      // 8,388,608 elems
    short* qsb = (short*)w8;                          // bf16, scaled by 1/8
    short* khb = (short*)(w8 + NH * 2);
    short* vtb = (short*)(w8 + NH * 4);               // [b,h,64,2048]
    float* mb  = (float*)(w8 + NH * 6);
    float* izb = mb + (size_t)BB * HH * SS;
    float* ctxb = izb + (size_t)BB * HH * SS;

    dim3 blk(256);
    dim3 gP(SS / 64, BB * HH);
    proj_bf<<<gP, blk, 0, stream>>>(q, Wq, bq, qsb, 0.125f);
    proj_bf<<<gP, blk, 0, stream>>>(k, Wk, bk, khb, 1.0f);
    proj_vT<<<gP, blk, 0, stream>>>(v, Wv, bv, vtb);
    stats_mfma<<<dim3(SS / 64, BB * HH), blk, 0, stream>>>(qsb, khb, mb, izb);
    ctx_mfma<<<dim3(SS / 128, BB * HH), blk, 0, stream>>>(qsb, khb, vtb, mb, izb, ctxb);
    out_kernel<<<dim3(BB * SS / 64, DM / 64), blk, 0, stream>>>(ctxb, Wo, bo, out);
}

// Round 3
// 329.416 us; speedup vs baseline: 31.5368x; 3.7085x over previous
//
#include <hip/hip_runtime.h>
#include <hip/hip_bf16.h>
#include <math.h>

#define BB 8
#define SS 2048
#define HH 8
#define DM 512
#define DK 64

typedef short bf16x8 __attribute__((ext_vector_type(8)));
typedef float f32x4 __attribute__((ext_vector_type(4)));

static __device__ __forceinline__ short f2bf(float f) {
    union { __hip_bfloat16 h; short s; } u;
    u.h = __float2bfloat16(f);
    return u.s;
}

// async 16B global->LDS (linear LDS dest = base + lane*16; global src per-lane)
static __device__ __forceinline__ void gld16(void* lds, const void* g) {
    __builtin_amdgcn_global_load_lds((const __attribute__((address_space(1))) void*)g,
                                     (__attribute__((address_space(3))) void*)lds, 16, 0, 0);
}

// swizzled read of 8 shorts from a [rows][64]-short LDS tile: slot ^= (row&7)
static __device__ __forceinline__ bf16x8 fragRow(const short* lds, int row, int cshort) {
    return *(const bf16x8*)(lds + row * 64 + (cshort ^ ((row & 7) << 3)));
}

// ds_write staging of a [64][64] bf16 tile from row-major global, swizzled
static __device__ __forceinline__ void stage64(short* lds, const short* g, int gstride, int t) {
#pragma unroll
    for (int p = 0; p < 2; ++p) {
        int idx = t + p * 256;
        int row = idx >> 3;
        int cs  = (idx & 7) << 3;
        bf16x8 v = *(const bf16x8*)(g + (size_t)row * gstride + cs);
        *(bf16x8*)(lds + row * 64 + (cs ^ ((row & 7) << 3))) = v;
    }
}

// ---------------- fp32 -> bf16 convert for q,k,v (grid.z selects tensor) ----------------
__global__ __launch_bounds__(256) void cvt3(const float* __restrict__ q, const float* __restrict__ k,
                                            const float* __restrict__ v, short* __restrict__ qd,
                                            short* __restrict__ kd, short* __restrict__ vd) {
    const int z = blockIdx.z;
    const float* src = z == 0 ? q : (z == 1 ? k : v);
    short* dst = z == 0 ? qd : (z == 1 ? kd : vd);
    size_t i = ((size_t)blockIdx.x * 256 + threadIdx.x) * 8;
    float4 a = *(const float4*)(src + i);
    float4 b = *(const float4*)(src + i + 4);
    bf16x8 o;
    o[0] = f2bf(a.x); o[1] = f2bf(a.y); o[2] = f2bf(a.z); o[3] = f2bf(a.w);
    o[4] = f2bf(b.x); o[5] = f2bf(b.y); o[6] = f2bf(b.z); o[7] = f2bf(b.w);
    *(bf16x8*)(dst + i) = o;
}

// ---------------- transpose-convert: src fp32 [R][C] -> dst bf16 [C][R] (per grid.z head) ----------------
__global__ __launch_bounds__(256) void tcvt(const float* __restrict__ src, short* __restrict__ dst,
                                            int R, int C, int srcHS, int dstHS) {
    __shared__ short T[64][72];   // 72-short row stride = 144B (16B-aligned chunks)
    src += (size_t)blockIdx.z * srcHS;
    dst += (size_t)blockIdx.z * dstHS;
    const int r0 = blockIdx.x * 64, c0 = blockIdx.y * 64;
    const int t = threadIdx.x;
#pragma unroll
    for (int p = 0; p < 4; ++p) {
        int idx = t + 256 * p;
        int row = idx >> 4, c4 = (idx & 15) * 4;
        float4 v = *(const float4*)(src + (size_t)(r0 + row) * C + c0 + c4);
        T[c4 + 0][row] = f2bf(v.x);
        T[c4 + 1][row] = f2bf(v.y);
        T[c4 + 2][row] = f2bf(v.z);
        T[c4 + 3][row] = f2bf(v.w);
    }
    __syncthreads();
#pragma unroll
    for (int p = 0; p < 2; ++p) {
        int idx = t + 256 * p;
        int row = idx >> 3, slot = idx & 7;
        *(bf16x8*)(dst + (size_t)(c0 + row) * R + r0 + slot * 8) = *(const bf16x8*)&T[row][slot * 8];
    }
}

// ---------------- projection GEMM, bf16 MFMA ----------------
// Y[s,n] = sum_k X[s,k] * W[k,n] + bias ; A = X rows, B = WT rows (n-entity, k-contig)
// mode 0: Q (scale 0.125, row-major [b,h,s,64]); 1: K (row-major); 2: V (transposed [b,h,64,s])
__global__ __launch_bounds__(256) void proj_mfma(const short* __restrict__ X,
                                                 const short* __restrict__ WT,
                                                 const float* __restrict__ bias,
                                                 short* __restrict__ Y, int mode) {
    __shared__ short As[128 * 64];
    __shared__ short Bs[64 * 64];
    const int bh = blockIdx.y;
    const int b = bh >> 3, h = bh & 7;
    const int s0 = blockIdx.x * 128;
    const int t = threadIdx.x;
    const int l = t & 63, w = t >> 6;
    const int lr = l & 15, g = l >> 4;
    const short* Xb = X + ((size_t)b * SS + s0) * DM;
    const short* Wh = WT + (size_t)h * DK * DM;   // [64][512]
    f32x4 acc[2][4];
#pragma unroll
    for (int i = 0; i < 2; ++i)
#pragma unroll
        for (int j = 0; j < 4; ++j) acc[i][j] = (f32x4){0.f, 0.f, 0.f, 0.f};

    for (int k0 = 0; k0 < DM; k0 += 64) {
        __syncthreads();
        // A tile 128x64: 1024 chunks; pre-swizzled source, linear LDS
#pragma unroll
        for (int p = 0; p < 4; ++p) {
            int c = p * 256 + w * 64 + l;
            int row = c >> 3, slot = c & 7;
            gld16(As + (size_t)(p * 256 + w * 64) * 8,
                  Xb + (size_t)row * DM + k0 + ((slot ^ (row & 7)) * 8));
        }
        // B tile 64x64: 512 chunks
#pragma unroll
        for (int p = 0; p < 2; ++p) {
            int c = p * 256 + w * 64 + l;
            int row = c >> 3, slot = c & 7;
            gld16(Bs + (size_t)(p * 256 + w * 64) * 8,
                  Wh + (size_t)row * DM + k0 + ((slot ^ (row & 7)) * 8));
        }
        __syncthreads();
        bf16x8 bfr[4][2];
#pragma unroll
        for (int bf = 0; bf < 4; ++bf) {
            bfr[bf][0] = fragRow(Bs, 16 * bf + lr, 8 * g);
            bfr[bf][1] = fragRow(Bs, 16 * bf + lr, 32 + 8 * g);
        }
#pragma unroll
        for (int af = 0; af < 2; ++af) {
            bf16x8 a0 = fragRow(As, 32 * w + 16 * af + lr, 8 * g);
            bf16x8 a1 = fragRow(As, 32 * w + 16 * af + lr, 32 + 8 * g);
#pragma unroll
            for (int bf = 0; bf < 4; ++bf) {
                acc[af][bf] = __builtin_amdgcn_mfma_f32_16x16x32_bf16(a0, bfr[bf][0], acc[af][bf], 0, 0, 0);
                acc[af][bf] = __builtin_amdgcn_mfma_f32_16x16x32_bf16(a1, bfr[bf][1], acc[af][bf], 0, 0, 0);
            }
        }
    }
    if (mode == 2) {
        short* Yb = Y + (size_t)bh * DK * SS;   // [64][2048]
#pragma unroll
        for (int qf = 0; qf < 2; ++qf)
#pragma unroll
            for (int nf = 0; nf < 4; ++nf) {
                int n = 16 * nf + lr;
                float bv = bias[h * DK + n];
                short4 o;
                o.x = f2bf(acc[qf][nf][0] + bv);
                o.y = f2bf(acc[qf][nf][1] + bv);
                o.z = f2bf(acc[qf][nf][2] + bv);
                o.w = f2bf(acc[qf][nf][3] + bv);
                *(short4*)(Yb + (size_t)n * SS + s0 + 32 * w + 16 * qf + 4 * g) = o;
            }
    } else {
        const float scale = (mode == 0) ? 0.125f : 1.0f;
        short* Yb = Y + ((size_t)bh * SS + s0) * DK;
#pragma unroll
        for (int qf = 0; qf < 2; ++qf)
#pragma unroll
            for (int nf = 0; nf < 4; ++nf) {
                int n = 16 * nf + lr;
                float bv = bias[h * DK + n];
#pragma unroll
                for (int r = 0; r < 4; ++r)
                    Yb[(size_t)(32 * w + 16 * qf + 4 * g + r) * DK + n] =
                        f2bf((acc[qf][nf][r] + bv) * scale);
            }
    }
}

// ---------------- output projection: [16384x512]bf16 @ WoT[512x512]bf16 + bo -> fp32 ----------------
__global__ __launch_bounds__(256) void out_mfma(const short* __restrict__ A,
                                                const short* __restrict__ BT,
                                                const float* __restrict__ bo,
                                                float* __restrict__ out) {
    __shared__ short As[128 * 64];
    __shared__ short Bs[128 * 64];
    const int r0 = blockIdx.x * 128;
    const int j0 = blockIdx.y * 128;
    const int t = threadIdx.x;
    const int l = t & 63, w = t >> 6;
    const int lr = l & 15, g = l >> 4;
    const int wr = w >> 1, wc = w & 1;
    f32x4 acc[4][4];
#pragma unroll
    for (int i = 0; i < 4; ++i)
#pragma unroll
        for (int j = 0; j < 4; ++j) acc[i][j] = (f32x4){0.f, 0.f, 0.f, 0.f};

    for (int k0 = 0; k0 < DM; k0 += 64) {
        __syncthreads();
#pragma unroll
        for (int p = 0; p < 4; ++p) {
            int c = p * 256 + w * 64 + l;
            int row = c >> 3, slot = c & 7;
            gld16(As + (size_t)(p * 256 + w * 64) * 8,
                  A + (size_t)(r0 + row) * DM + k0 + ((slot ^ (row & 7)) * 8));
            gld16(Bs + (size_t)(p * 256 + w * 64) * 8,
                  BT + (size_t)(j0 + row) * DM + k0 + ((slot ^ (row & 7)) * 8));
        }
        __syncthreads();
        bf16x8 bfr[4][2];
#pragma unroll
        for (int bf = 0; bf < 4; ++bf) {
            bfr[bf][0] = fragRow(Bs, 64 * wc + 16 * bf + lr, 8 * g);
            bfr[bf][1] = fragRow(Bs, 64 * wc + 16 * bf + lr, 32 + 8 * g);
        }
#pragma unroll
        for (int af = 0; af < 4; ++af) {
            bf16x8 a0 = fragRow(As, 64 * wr + 16 * af + lr, 8 * g);
            bf16x8 a1 = fragRow(As, 64 * wr + 16 * af + lr, 32 + 8 * g);
#pragma unroll
            for (int bf = 0; bf < 4; ++bf) {
                acc[af][bf] = __builtin_amdgcn_mfma_f32_16x16x32_bf16(a0, bfr[bf][0], acc[af][bf], 0, 0, 0);
                acc[af][bf] = __builtin_amdgcn_mfma_f32_16x16x32_bf16(a1, bfr[bf][1], acc[af][bf], 0, 0, 0);
            }
        }
    }
#pragma unroll
    for (int af = 0; af < 4; ++af)
#pragma unroll
        for (int bf = 0; bf < 4; ++bf) {
            int j = j0 + 64 * wc + 16 * bf + lr;
            float bv = bo[j];
#pragma unroll
            for (int r = 0; r < 4; ++r)
                out[(size_t)(r0 + 64 * wr + 16 * af + 4 * g + r) * DM + j] = acc[af][bf][r] + bv;
        }
}

// ---------------- stats: per-key m / 1/Z over the QUERY axis (MFMA) ----------------
__global__ __launch_bounds__(256) void stats_mfma(const short* __restrict__ qs,
                                                  const short* __restrict__ kh,
                                                  float* __restrict__ mOut,
                                                  float* __restrict__ izOut) {
    __shared__ short Ks[64 * 64];
    __shared__ short Qs[64 * 64];
    const int bh = blockIdx.y;
    const int k0 = blockIdx.x * 64;
    const int t = threadIdx.x;
    const int l = t & 63;
    const int w = t >> 6;
    const int lr = l & 15;
    const int g = l >> 4;
    const short* Qb = qs + (size_t)bh * SS * DK;
    const short* Kb = kh + ((size_t)bh * SS + k0) * DK;

    stage64(Ks, Kb, DK, t);
    __syncthreads();
    bf16x8 bk0 = fragRow(Ks, 16 * w + lr, 8 * g);
    bf16x8 bk1 = fragRow(Ks, 16 * w + lr, 32 + 8 * g);

    float mt = -INFINITY, zt = 0.f;
    for (int q0 = 0; q0 < SS; q0 += 64) {
        __syncthreads();
        stage64(Qs, Qb + (size_t)q0 * DK, DK, t);
        __syncthreads();
#pragma unroll
        for (int qf = 0; qf < 4; ++qf) {
            bf16x8 aq0 = fragRow(Qs, 16 * qf + lr, 8 * g);
            bf16x8 aq1 = fragRow(Qs, 16 * qf + lr, 32 + 8 * g);
            f32x4 s = {0.f, 0.f, 0.f, 0.f};
            s = __builtin_amdgcn_mfma_f32_16x16x32_bf16(aq0, bk0, s, 0, 0, 0);
            s = __builtin_amdgcn_mfma_f32_16x16x32_bf16(aq1, bk1, s, 0, 0, 0);
#pragma unroll
            for (int r = 0; r < 4; ++r) {
                float sv = s[r];
                float nm = fmaxf(mt, sv);
                zt = zt * __expf(mt - nm) + __expf(sv - nm);
                mt = nm;
            }
        }
    }
#pragma unroll
    for (int off = 16; off <= 32; off <<= 1) {
        float om = __shfl_xor(mt, off);
        float oz = __shfl_xor(zt, off);
        float nm = fmaxf(mt, om);
        zt = zt * __expf(mt - nm) + oz * __expf(om - nm);
        mt = nm;
    }
    if (l < 16) {
        mOut[(size_t)bh * SS + k0 + 16 * w + l] = mt;
        izOut[(size_t)bh * SS + k0 + 16 * w + l] = 1.f / zt;
    }
}

// ---------------- ctx: P = exp(S-m[k])*invz[k]; ctx = P @ V ; bf16 concat-layout output ----------------
__global__ __launch_bounds__(256) void ctx_mfma(const short* __restrict__ qs,
                                                const short* __restrict__ kh,
                                                const short* __restrict__ vT,
                                                const float* __restrict__ mArr,
                                                const float* __restrict__ izArr,
                                                short* __restrict__ ctxc) {
    __shared__ short Qs[128 * 64];
    __shared__ short Ks[64 * 64];
    __shared__ short Vs[64 * 64];
    const int bh = blockIdx.y;
    const int b = bh >> 3, h = bh & 7;
    const int q0 = blockIdx.x * 128;
    const int t = threadIdx.x;
    const int l = t & 63;
    const int w = t >> 6;
    const int lr = l & 15;
    const int g = l >> 4;
    const short* Qb = qs + ((size_t)bh * SS + q0) * DK;
    const short* Kb = kh + (size_t)bh * SS * DK;
    const short* Vb = vT + (size_t)bh * DK * SS;
    const float* mB = mArr + (size_t)bh * SS;
    const float* zB = izArr + (size_t)bh * SS;

#pragma unroll
    for (int p = 0; p < 4; ++p) {
        int idx = t + p * 256;
        int row = idx >> 3;
        int cs = (idx & 7) << 3;
        *(bf16x8*)(Qs + row * 64 + (cs ^ ((row & 7) << 3))) = *(const bf16x8*)(Qb + (size_t)row * DK + cs);
    }
    __syncthreads();
    bf16x8 qfr[2][2];
#pragma unroll
    for (int qf = 0; qf < 2; ++qf)
#pragma unroll
        for (int c = 0; c < 2; ++c)
            qfr[qf][c] = fragRow(Qs, 32 * w + 16 * qf + lr, 32 * c + 8 * g);

    f32x4 acc[2][4];
#pragma unroll
    for (int a = 0; a < 2; ++a)
#pragma unroll
        for (int b2 = 0; b2 < 4; ++b2) acc[a][b2] = (f32x4){0.f, 0.f, 0.f, 0.f};

    for (int k0 = 0; k0 < SS; k0 += 64) {
        __syncthreads();
        stage64(Ks, Kb + (size_t)k0 * DK, DK, t);
        stage64(Vs, Vb + k0, SS, t);
        __syncthreads();

        float pw[2][4][4];
#pragma unroll
        for (int kf = 0; kf < 4; ++kf) {
            bf16x8 ak0 = fragRow(Ks, 16 * kf + lr, 8 * g);
            bf16x8 ak1 = fragRow(Ks, 16 * kf + lr, 32 + 8 * g);
            f32x4 m4 = *(const f32x4*)(mB + k0 + 16 * kf + 4 * g);
            f32x4 z4 = *(const f32x4*)(zB + k0 + 16 * kf + 4 * g);
#pragma unroll
            for (int qf = 0; qf < 2; ++qf) {
                f32x4 s = {0.f, 0.f, 0.f, 0.f};
                s = __builtin_amdgcn_mfma_f32_16x16x32_bf16(ak0, qfr[qf][0], s, 0, 0, 0);
                s = __builtin_amdgcn_mfma_f32_16x16x32_bf16(ak1, qfr[qf][1], s, 0, 0, 0);
#pragma unroll
                for (int r = 0; r < 4; ++r)
                    pw[qf][kf][r] = __expf(s[r] - m4[r]) * z4[r];
            }
        }
        bf16x8 pa[2][2];
#pragma unroll
        for (int qf = 0; qf < 2; ++qf)
#pragma unroll
            for (int c = 0; c < 2; ++c) {
#pragma unroll
                for (int e = 0; e < 4; ++e) {
                    pa[qf][c][e]     = f2bf(pw[qf][2 * c][e]);
                    pa[qf][c][4 + e] = f2bf(pw[qf][2 * c + 1][e]);
                }
            }
#pragma unroll
        for (int vf = 0; vf < 4; ++vf) {
            const int rowv = 16 * vf + lr;
            const int swz = (rowv & 7) << 3;
#pragma unroll
            for (int c = 0; c < 2; ++c) {
                ushort4 lo = *(const ushort4*)(Vs + rowv * 64 + ((32 * c + 4 * g) ^ swz));
                ushort4 hi = *(const ushort4*)(Vs + rowv * 64 + ((32 * c + 16 + 4 * g) ^ swz));
                bf16x8 bv;
                bv[0] = lo.x; bv[1] = lo.y; bv[2] = lo.z; bv[3] = lo.w;
                bv[4] = hi.x; bv[5] = hi.y; bv[6] = hi.z; bv[7] = hi.w;
#pragma unroll
                for (int qf = 0; qf < 2; ++qf)
                    acc[qf][vf] = __builtin_amdgcn_mfma_f32_16x16x32_bf16(pa[qf][c], bv, acc[qf][vf], 0, 0, 0);
            }
        }
    }
    // write bf16 in concat layout [b, s, h*64+v]
    short* Cb = ctxc + ((size_t)b * SS + q0) * (HH * DK) + h * DK;
#pragma unroll
    for (int qf = 0; qf < 2; ++qf)
#pragma unroll
        for (int vf = 0; vf < 4; ++vf)
#pragma unroll
            for (int r = 0; r < 4; ++r)
                Cb[(size_t)(32 * w + 16 * qf + 4 * g + r) * (HH * DK) + 16 * vf + lr] =
                    f2bf(acc[qf][vf][r]);
}

extern "C" void kernel_launch(void* const* d_in, const int* in_sizes, int n_in,
                              void* d_out, int out_size, void* d_ws, size_t ws_size,
                              hipStream_t stream) {
    const float* q  = (const float*)d_in[0];
    const float* k  = (const float*)d_in[1];
    const float* v  = (const float*)d_in[2];
    const float* Wq = (const float*)d_in[3];
    const float* bq = (const float*)d_in[4];
    const float* Wk = (const float*)d_in[5];
    const float* bk = (const float*)d_in[6];
    const float* Wv = (const float*)d_in[7];
    const float* bv = (const float*)d_in[8];
    const float* Wo = (const float*)d_in[9];
    const float* bo = (const float*)d_in[10];
    float* out = (float*)d_out;

    short* w16 = (short*)d_ws;
    const size_t NX = (size_t)BB * SS * DM;       // 8,388,608
    const size_t NH = (size_t)BB * HH * SS * DK;  // 8,388,608
    const size_t NW = (size_t)HH * DM * DK;       // 262,144
    short* qb  = w16;
    short* kb  = w16 + NX;
    short* vb  = w16 + 2 * NX;
    short* WqT = w16 + 3 * NX;
    short* WkT = WqT + NW;
    short* WvT = WkT + NW;
    short* WoT = WvT + NW;
    short* qsb = WoT + NW;
    short* khb = qsb + NH;
    short* vtb = khb + NH;
    short* ctc = vtb + NH;
    float* mb  = (float*)(ctc + NH);
    float* izb = mb + (size_t)BB * HH * SS;

    dim3 blk(256);
    cvt3<<<dim3(NX / (256 * 8), 1, 3), blk, 0, stream>>>(q, k, v, qb, kb, vb);
    tcvt<<<dim3(8, 1, 8), blk, 0, stream>>>(Wq, WqT, DM, DK, DM * DK, DK * DM);
    tcvt<<<dim3(8, 1, 8), blk, 0, stream>>>(Wk, WkT, DM, DK, DM * DK, DK * DM);
    tcvt<<<dim3(8, 1, 8), blk, 0, stream>>>(Wv, WvT, DM, DK, DM * DK, DK * DM);
    tcvt<<<dim3(8, 8, 1), blk, 0, stream>>>(Wo, WoT, DM, DM, 0, 0);
    proj_mfma<<<dim3(SS / 128, BB * HH), blk, 0, stream>>>(qb, WqT, bq, qsb, 0);
    proj_mfma<<<dim3(SS / 128, BB * HH), blk, 0, stream>>>(kb, WkT, bk, khb, 1);
    proj_mfma<<<dim3(SS / 128, BB * HH), blk, 0, stream>>>(vb, WvT, bv, vtb, 2);
    stats_mfma<<<dim3(SS / 64, BB * HH), blk, 0, stream>>>(qsb, khb, mb, izb);
    ctx_mfma<<<dim3(SS / 128, BB * HH), blk, 0, stream>>>(qsb, khb, vtb, mb, izb, ctc);
    out_mfma<<<dim3(BB * SS / 128, DM / 128), blk, 0, stream>>>(ctc, WoT, bo, out);
}

// Round 4
// 233.008 us; speedup vs baseline: 44.5853x; 1.4138x over previous
//
#include <hip/hip_runtime.h>
#include <hip/hip_bf16.h>
#include <math.h>

#define BB 8
#define SS 2048
#define HH 8
#define DM 512
#define DK 64

typedef short bf16x8 __attribute__((ext_vector_type(8)));
typedef float f32x4 __attribute__((ext_vector_type(4)));

static __device__ __forceinline__ short f2bf(float f) {
    union { __hip_bfloat16 h; short s; } u;
    u.h = __float2bfloat16(f);
    return u.s;
}

// exp2 (v_exp_f32); scores are pre-scaled by log2e so softmax base matches e
static __device__ __forceinline__ float fexp2(float x) {
#if __has_builtin(__builtin_amdgcn_exp2f)
    return __builtin_amdgcn_exp2f(x);
#else
    return __expf(x * 0.69314718056f);
#endif
}

// async 16B global->LDS; LDS dest must be wave-uniform base (+lane*16 implicit)
static __device__ __forceinline__ void gld16(void* lds, const void* g) {
    __builtin_amdgcn_global_load_lds((const __attribute__((address_space(1))) void*)g,
                                     (__attribute__((address_space(3))) void*)lds, 16, 0, 0);
}

// swizzled read of 8 shorts from a [rows][64]-short LDS tile: 16B slot ^= (row&7)
static __device__ __forceinline__ bf16x8 fragRow(const short* lds, int row, int cshort) {
    return *(const bf16x8*)(lds + row * 64 + (cshort ^ ((row & 7) << 3)));
}

#define VMCNT0 asm volatile("s_waitcnt vmcnt(0)" ::: "memory")

// ---------------- fp32 -> bf16 convert for q,k,v ----------------
__global__ __launch_bounds__(256) void cvt3(const float* __restrict__ q, const float* __restrict__ k,
                                            const float* __restrict__ v, short* __restrict__ qd,
                                            short* __restrict__ kd, short* __restrict__ vd) {
    const int z = blockIdx.z;
    const float* src = z == 0 ? q : (z == 1 ? k : v);
    short* dst = z == 0 ? qd : (z == 1 ? kd : vd);
    size_t i = ((size_t)blockIdx.x * 256 + threadIdx.x) * 8;
    float4 a = *(const float4*)(src + i);
    float4 b = *(const float4*)(src + i + 4);
    bf16x8 o;
    o[0] = f2bf(a.x); o[1] = f2bf(a.y); o[2] = f2bf(a.z); o[3] = f2bf(a.w);
    o[4] = f2bf(b.x); o[5] = f2bf(b.y); o[6] = f2bf(b.z); o[7] = f2bf(b.w);
    *(bf16x8*)(dst + i) = o;
}

// ---------------- transpose-convert: fp32 [R][C] -> bf16 [C][R] (per grid.z head) ----------------
__global__ __launch_bounds__(256) void tcvt(const float* __restrict__ src, short* __restrict__ dst,
                                            int R, int C, int srcHS, int dstHS) {
    __shared__ short T[64][72];
    src += (size_t)blockIdx.z * srcHS;
    dst += (size_t)blockIdx.z * dstHS;
    const int r0 = blockIdx.x * 64, c0 = blockIdx.y * 64;
    const int t = threadIdx.x;
#pragma unroll
    for (int p = 0; p < 4; ++p) {
        int idx = t + 256 * p;
        int row = idx >> 4, c4 = (idx & 15) * 4;
        float4 v = *(const float4*)(src + (size_t)(r0 + row) * C + c0 + c4);
        T[c4 + 0][row] = f2bf(v.x);
        T[c4 + 1][row] = f2bf(v.y);
        T[c4 + 2][row] = f2bf(v.z);
        T[c4 + 3][row] = f2bf(v.w);
    }
    __syncthreads();
#pragma unroll
    for (int p = 0; p < 2; ++p) {
        int idx = t + 256 * p;
        int row = idx >> 3, slot = idx & 7;
        *(bf16x8*)(dst + (size_t)(c0 + row) * R + r0 + slot * 8) = *(const bf16x8*)&T[row][slot * 8];
    }
}

// ---------------- projection GEMM, bf16 MFMA, 2-phase dbuf ----------------
// mode 0/1: row-major [b,h,s,64] (Q scaled); mode 2: V^T [b,h,64,s] with k-PERMUTED cols
__global__ __launch_bounds__(256, 3) void proj_mfma(const short* __restrict__ X,
                                                    const short* __restrict__ WT,
                                                    const float* __restrict__ bias,
                                                    short* __restrict__ Y, float scale, int mode) {
    __shared__ short As[2][128 * 64];
    __shared__ short Bs[2][64 * 64];
    const int lin = blockIdx.y * 16 + blockIdx.x;
    const int b = lin & 7, h = (lin >> 3) & 7;      // XCD-clustered: X[b] stays in one L2
    const int s0 = (lin >> 6) * 128;
    const int bh = b * 8 + h;
    const int t = threadIdx.x;
    const int l = t & 63, w = t >> 6;
    const int lr = l & 15, g = l >> 4;
    const short* Xb = X + ((size_t)b * SS + s0) * DM;
    const short* Wh = WT + (size_t)h * DK * DM;
    f32x4 acc[2][4];
#pragma unroll
    for (int i = 0; i < 2; ++i)
#pragma unroll
        for (int j = 0; j < 4; ++j) acc[i][j] = (f32x4){0.f, 0.f, 0.f, 0.f};

    auto stage = [&](int buf, int k0) {
#pragma unroll
        for (int p = 0; p < 4; ++p) {
            int c = p * 256 + w * 64 + l;
            int row = c >> 3, slot = c & 7;
            gld16(As[buf] + (size_t)(p * 256 + w * 64) * 8,
                  Xb + (size_t)row * DM + k0 + ((slot ^ (row & 7)) * 8));
        }
#pragma unroll
        for (int p = 0; p < 2; ++p) {
            int c = p * 256 + w * 64 + l;
            int row = c >> 3, slot = c & 7;
            gld16(Bs[buf] + (size_t)(p * 256 + w * 64) * 8,
                  Wh + (size_t)row * DM + k0 + ((slot ^ (row & 7)) * 8));
        }
    };
    stage(0, 0);
    VMCNT0;
    __syncthreads();
    int cur = 0;
    for (int k0 = 0; k0 < DM; k0 += 64) {
        if (k0 + 64 < DM) stage(cur ^ 1, k0 + 64);
        bf16x8 bfr[4][2];
#pragma unroll
        for (int bf = 0; bf < 4; ++bf) {
            bfr[bf][0] = fragRow(Bs[cur], 16 * bf + lr, 8 * g);
            bfr[bf][1] = fragRow(Bs[cur], 16 * bf + lr, 32 + 8 * g);
        }
#pragma unroll
        for (int af = 0; af < 2; ++af) {
            bf16x8 a0 = fragRow(As[cur], 32 * w + 16 * af + lr, 8 * g);
            bf16x8 a1 = fragRow(As[cur], 32 * w + 16 * af + lr, 32 + 8 * g);
#pragma unroll
            for (int bf = 0; bf < 4; ++bf) {
                acc[af][bf] = __builtin_amdgcn_mfma_f32_16x16x32_bf16(a0, bfr[bf][0], acc[af][bf], 0, 0, 0);
                acc[af][bf] = __builtin_amdgcn_mfma_f32_16x16x32_bf16(a1, bfr[bf][1], acc[af][bf], 0, 0, 0);
            }
        }
        VMCNT0;
        __syncthreads();
        cur ^= 1;
    }
    if (mode == 2) {
        // V^T with within-32 k-permutation: offset 16qf+4g+r stored at 8g+4qf+r
        short* Yb = Y + (size_t)bh * DK * SS;
#pragma unroll
        for (int qf = 0; qf < 2; ++qf)
#pragma unroll
            for (int nf = 0; nf < 4; ++nf) {
                int n = 16 * nf + lr;
                float bv = bias[h * DK + n];
                short4 o;
                o.x = f2bf(acc[qf][nf][0] + bv);
                o.y = f2bf(acc[qf][nf][1] + bv);
                o.z = f2bf(acc[qf][nf][2] + bv);
                o.w = f2bf(acc[qf][nf][3] + bv);
                *(short4*)(Yb + (size_t)n * SS + s0 + 32 * w + 8 * g + 4 * qf) = o;
            }
    } else {
        short* Yb = Y + ((size_t)bh * SS + s0) * DK;
#pragma unroll
        for (int qf = 0; qf < 2; ++qf)
#pragma unroll
            for (int nf = 0; nf < 4; ++nf) {
                int n = 16 * nf + lr;
                float bv = bias[h * DK + n];
#pragma unroll
                for (int r = 0; r < 4; ++r)
                    Yb[(size_t)(32 * w + 16 * qf + 4 * g + r) * DK + n] =
                        f2bf((acc[qf][nf][r] + bv) * scale);
            }
    }
}

// ---------------- stats: z[k] = sum_q 2^s' (no max needed, |s| small); 128 k-cols/block ----------------
__global__ __launch_bounds__(256, 4) void stats_mfma(const short* __restrict__ qs,
                                                     const short* __restrict__ kh,
                                                     float* __restrict__ izOut) {
    __shared__ short Ks[128 * 64];
    __shared__ short Qs[2][64 * 64];
    const int lin = blockIdx.y * 16 + blockIdx.x;
    const int bh = ((lin >> 7) << 3) | (lin & 7);   // XCD-clustered per bh
    const int k0 = ((lin >> 3) & 15) * 128;
    const int t = threadIdx.x;
    const int l = t & 63, w = t >> 6;
    const int lr = l & 15, g = l >> 4;
    const short* Qb = qs + (size_t)bh * SS * DK;
    const short* Kb = kh + ((size_t)bh * SS + k0) * DK;
#pragma unroll
    for (int p = 0; p < 4; ++p) {
        int c = p * 256 + w * 64 + l;
        int row = c >> 3, slot = c & 7;
        gld16(Ks + (size_t)(p * 256 + w * 64) * 8,
              Kb + (size_t)row * DK + ((slot ^ (row & 7)) * 8));
    }
    auto stageQ = [&](int buf, int qq) {
#pragma unroll
        for (int p = 0; p < 2; ++p) {
            int c = p * 256 + w * 64 + l;
            int row = c >> 3, slot = c & 7;
            gld16(Qs[buf] + (size_t)(p * 256 + w * 64) * 8,
                  Qb + (size_t)(qq + row) * DK + ((slot ^ (row & 7)) * 8));
        }
    };
    stageQ(0, 0);
    VMCNT0;
    __syncthreads();
    bf16x8 bk[2][2];
#pragma unroll
    for (int c2 = 0; c2 < 2; ++c2) {
        bk[c2][0] = fragRow(Ks, 32 * w + 16 * c2 + lr, 8 * g);
        bk[c2][1] = fragRow(Ks, 32 * w + 16 * c2 + lr, 32 + 8 * g);
    }
    f32x4 zacc[2];
    zacc[0] = (f32x4){0.f, 0.f, 0.f, 0.f};
    zacc[1] = (f32x4){0.f, 0.f, 0.f, 0.f};
    int cur = 0;
    for (int q0 = 0; q0 < SS; q0 += 64) {
        if (q0 + 64 < SS) stageQ(cur ^ 1, q0 + 64);
#pragma unroll
        for (int qf = 0; qf < 4; ++qf) {
            bf16x8 aq0 = fragRow(Qs[cur], 16 * qf + lr, 8 * g);
            bf16x8 aq1 = fragRow(Qs[cur], 16 * qf + lr, 32 + 8 * g);
#pragma unroll
            for (int c2 = 0; c2 < 2; ++c2) {
                f32x4 s = {0.f, 0.f, 0.f, 0.f};
                s = __builtin_amdgcn_mfma_f32_16x16x32_bf16(aq0, bk[c2][0], s, 0, 0, 0);
                s = __builtin_amdgcn_mfma_f32_16x16x32_bf16(aq1, bk[c2][1], s, 0, 0, 0);
#pragma unroll
                for (int r = 0; r < 4; ++r)
                    zacc[c2][r] += fexp2(s[r]);
            }
        }
        VMCNT0;
        __syncthreads();
        cur ^= 1;
    }
#pragma unroll
    for (int c2 = 0; c2 < 2; ++c2) {
        float z = zacc[c2][0] + zacc[c2][1] + zacc[c2][2] + zacc[c2][3];
        z += __shfl_xor(z, 16);
        z += __shfl_xor(z, 32);
        if (l < 16)
            izOut[(size_t)bh * SS + k0 + 32 * w + 16 * c2 + l] = 1.f / z;
    }
}

// ---------------- ctx: P = 2^s' * iz[k]; ctx = P @ V ; swapped QK^T, permuted-V, 2-phase ----------------
__global__ __launch_bounds__(256, 3) void ctx_mfma(const short* __restrict__ qs,
                                                   const short* __restrict__ kh,
                                                   const short* __restrict__ vP,
                                                   const float* __restrict__ izArr,
                                                   short* __restrict__ ctxc) {
    __shared__ short Qs[128 * 64];
    __shared__ short Ks[2][64 * 64];
    __shared__ short Vs[2][64 * 64];
    const int lin = blockIdx.y * 16 + blockIdx.x;
    const int bh = ((lin >> 7) << 3) | (lin & 7);
    const int q0 = ((lin >> 3) & 15) * 128;
    const int b = bh >> 3, h = bh & 7;
    const int t = threadIdx.x;
    const int l = t & 63, w = t >> 6;
    const int lr = l & 15, g = l >> 4;
    const short* Qb = qs + ((size_t)bh * SS + q0) * DK;
    const short* Kb = kh + (size_t)bh * SS * DK;
    const short* Vb = vP + (size_t)bh * DK * SS;
    const float* zB = izArr + (size_t)bh * SS;

#pragma unroll
    for (int p = 0; p < 4; ++p) {
        int c = p * 256 + w * 64 + l;
        int row = c >> 3, slot = c & 7;
        gld16(Qs + (size_t)(p * 256 + w * 64) * 8,
              Qb + (size_t)row * DK + ((slot ^ (row & 7)) * 8));
    }
    auto stageKV = [&](int buf, int kk) {
#pragma unroll
        for (int p = 0; p < 2; ++p) {
            int c = p * 256 + w * 64 + l;
            int row = c >> 3, slot = c & 7;
            gld16(Ks[buf] + (size_t)(p * 256 + w * 64) * 8,
                  Kb + (size_t)(kk + row) * DK + ((slot ^ (row & 7)) * 8));
        }
#pragma unroll
        for (int p = 0; p < 2; ++p) {
            int c = p * 256 + w * 64 + l;
            int row = c >> 3, slot = c & 7;
            gld16(Vs[buf] + (size_t)(p * 256 + w * 64) * 8,
                  Vb + (size_t)row * SS + kk + ((slot ^ (row & 7)) * 8));
        }
    };
    stageKV(0, 0);
    VMCNT0;
    __syncthreads();

    bf16x8 qfr[2][2];
#pragma unroll
    for (int qf = 0; qf < 2; ++qf)
#pragma unroll
        for (int c = 0; c < 2; ++c)
            qfr[qf][c] = fragRow(Qs, 32 * w + 16 * qf + lr, 32 * c + 8 * g);

    f32x4 acc[2][4];
#pragma unroll
    for (int a = 0; a < 2; ++a)
#pragma unroll
        for (int b2 = 0; b2 < 4; ++b2) acc[a][b2] = (f32x4){0.f, 0.f, 0.f, 0.f};

    int cur = 0;
    for (int k0 = 0; k0 < SS; k0 += 64) {
        // iz loads issued BEFORE next-tile staging so their wait doesn't drain the pipe
        f32x4 z4[4];
#pragma unroll
        for (int kf = 0; kf < 4; ++kf)
            z4[kf] = *(const f32x4*)(zB + k0 + 16 * kf + 4 * g);
        if (k0 + 64 < SS) stageKV(cur ^ 1, k0 + 64);

        // S phase (swapped: rows=k, cols=q; lane holds k = 16kf+4g+r for q=32w+16qf+lr)
        float pw[2][4][4];
#pragma unroll
        for (int kf = 0; kf < 4; ++kf) {
            bf16x8 ak0 = fragRow(Ks[cur], 16 * kf + lr, 8 * g);
            bf16x8 ak1 = fragRow(Ks[cur], 16 * kf + lr, 32 + 8 * g);
#pragma unroll
            for (int qf = 0; qf < 2; ++qf) {
                f32x4 s = {0.f, 0.f, 0.f, 0.f};
                s = __builtin_amdgcn_mfma_f32_16x16x32_bf16(ak0, qfr[qf][0], s, 0, 0, 0);
                s = __builtin_amdgcn_mfma_f32_16x16x32_bf16(ak1, qfr[qf][1], s, 0, 0, 0);
#pragma unroll
                for (int r = 0; r < 4; ++r)
                    pw[qf][kf][r] = fexp2(s[r]) * z4[kf][r];
            }
        }
        // pack P into A-frags; k-mapping e -> 32c + 16(e>>2) + 4g + (e&3)
        bf16x8 pa[2][2];
#pragma unroll
        for (int qf = 0; qf < 2; ++qf)
#pragma unroll
            for (int c = 0; c < 2; ++c) {
#pragma unroll
                for (int e = 0; e < 4; ++e) {
                    pa[qf][c][e]     = f2bf(pw[qf][2 * c][e]);
                    pa[qf][c][4 + e] = f2bf(pw[qf][2 * c + 1][e]);
                }
            }
        // PV: V pre-permuted in global -> standard contiguous swizzled read
#pragma unroll
        for (int vf = 0; vf < 4; ++vf) {
#pragma unroll
            for (int c = 0; c < 2; ++c) {
                bf16x8 bv = fragRow(Vs[cur], 16 * vf + lr, 32 * c + 8 * g);
#pragma unroll
                for (int qf = 0; qf < 2; ++qf)
                    acc[qf][vf] = __builtin_amdgcn_mfma_f32_16x16x32_bf16(pa[qf][c], bv, acc[qf][vf], 0, 0, 0);
            }
        }
        VMCNT0;
        __syncthreads();
        cur ^= 1;
    }
    // bf16 concat-layout write [b, s, h*64+v]
    short* Cb = ctxc + ((size_t)b * SS + q0) * (HH * DK) + h * DK;
#pragma unroll
    for (int qf = 0; qf < 2; ++qf)
#pragma unroll
        for (int vf = 0; vf < 4; ++vf)
#pragma unroll
            for (int r = 0; r < 4; ++r)
                Cb[(size_t)(32 * w + 16 * qf + 4 * g + r) * (HH * DK) + 16 * vf + lr] =
                    f2bf(acc[qf][vf][r]);
}

// ---------------- output projection: [16384x512]bf16 @ WoT + bo -> fp32, 2-phase ----------------
__global__ __launch_bounds__(256) void out_mfma(const short* __restrict__ A,
                                                const short* __restrict__ BT,
                                                const float* __restrict__ bo,
                                                float* __restrict__ out) {
    __shared__ short As[2][128 * 64];
    __shared__ short Bs[2][128 * 64];
    const int r0 = blockIdx.x * 128;
    const int j0 = blockIdx.y * 128;
    const int t = threadIdx.x;
    const int l = t & 63, w = t >> 6;
    const int lr = l & 15, g = l >> 4;
    const int wr = w >> 1, wc = w & 1;
    f32x4 acc[4][4];
#pragma unroll
    for (int i = 0; i < 4; ++i)
#pragma unroll
        for (int j = 0; j < 4; ++j) acc[i][j] = (f32x4){0.f, 0.f, 0.f, 0.f};

    auto stage = [&](int buf, int k0) {
#pragma unroll
        for (int p = 0; p < 4; ++p) {
            int c = p * 256 + w * 64 + l;
            int row = c >> 3, slot = c & 7;
            gld16(As[buf] + (size_t)(p * 256 + w * 64) * 8,
                  A + (size_t)(r0 + row) * DM + k0 + ((slot ^ (row & 7)) * 8));
            gld16(Bs[buf] + (size_t)(p * 256 + w * 64) * 8,
                  BT + (size_t)(j0 + row) * DM + k0 + ((slot ^ (row & 7)) * 8));
        }
    };
    stage(0, 0);
    VMCNT0;
    __syncthreads();
    int cur = 0;
    for (int k0 = 0; k0 < DM; k0 += 64) {
        if (k0 + 64 < DM) stage(cur ^ 1, k0 + 64);
        bf16x8 bfr[4][2];
#pragma unroll
        for (int bf = 0; bf < 4; ++bf) {
            bfr[bf][0] = fragRow(Bs[cur], 64 * wc + 16 * bf + lr, 8 * g);
            bfr[bf][1] = fragRow(Bs[cur], 64 * wc + 16 * bf + lr, 32 + 8 * g);
        }
#pragma unroll
        for (int af = 0; af < 4; ++af) {
            bf16x8 a0 = fragRow(As[cur], 64 * wr + 16 * af + lr, 8 * g);
            bf16x8 a1 = fragRow(As[cur], 64 * wr + 16 * af + lr, 32 + 8 * g);
#pragma unroll
            for (int bf = 0; bf < 4; ++bf) {
                acc[af][bf] = __builtin_amdgcn_mfma_f32_16x16x32_bf16(a0, bfr[bf][0], acc[af][bf], 0, 0, 0);
                acc[af][bf] = __builtin_amdgcn_mfma_f32_16x16x32_bf16(a1, bfr[bf][1], acc[af][bf], 0, 0, 0);
            }
        }
        VMCNT0;
        __syncthreads();
        cur ^= 1;
    }
#pragma unroll
    for (int af = 0; af < 4; ++af)
#pragma unroll
        for (int bf = 0; bf < 4; ++bf) {
            int j = j0 + 64 * wc + 16 * bf + lr;
            float bv = bo[j];
#pragma unroll
            for (int r = 0; r < 4; ++r)
                out[(size_t)(r0 + 64 * wr + 16 * af + 4 * g + r) * DM + j] = acc[af][bf][r] + bv;
        }
}

extern "C" void kernel_launch(void* const* d_in, const int* in_sizes, int n_in,
                              void* d_out, int out_size, void* d_ws, size_t ws_size,
                              hipStream_t stream) {
    const float* q  = (const float*)d_in[0];
    const float* k  = (const float*)d_in[1];
    const float* v  = (const float*)d_in[2];
    const float* Wq = (const float*)d_in[3];
    const float* bq = (const float*)d_in[4];
    const float* Wk = (const float*)d_in[5];
    const float* bk = (const float*)d_in[6];
    const float* Wv = (const float*)d_in[7];
    const float* bv = (const float*)d_in[8];
    const float* Wo = (const float*)d_in[9];
    const float* bo = (const float*)d_in[10];
    float* out = (float*)d_out;

    short* w16 = (short*)d_ws;
    const size_t NX = (size_t)BB * SS * DM;
    const size_t NH = (size_t)BB * HH * SS * DK;
    const size_t NW = (size_t)HH * DM * DK;
    short* qb  = w16;
    short* kb  = w16 + NX;
    short* vb  = w16 + 2 * NX;
    short* WqT = w16 + 3 * NX;
    short* WkT = WqT + NW;
    short* WvT = WkT + NW;
    short* WoT = WvT + NW;
    short* qsb = WoT + NW;
    short* khb = qsb + NH;
    short* vtb = khb + NH;
    short* ctc = vtb + NH;
    float* izb = (float*)(ctc + NH);

    const float qscale = 0.125f * 1.4426950408889634f;   // fold 1/sqrt(dk) and log2e

    dim3 blk(256);
    cvt3<<<dim3(NX / (256 * 8), 1, 3), blk, 0, stream>>>(q, k, v, qb, kb, vb);
    tcvt<<<dim3(8, 1, 8), blk, 0, stream>>>(Wq, WqT, DM, DK, DM * DK, DK * DM);
    tcvt<<<dim3(8, 1, 8), blk, 0, stream>>>(Wk, WkT, DM, DK, DM * DK, DK * DM);
    tcvt<<<dim3(8, 1, 8), blk, 0, stream>>>(Wv, WvT, DM, DK, DM * DK, DK * DM);
    tcvt<<<dim3(8, 8, 1), blk, 0, stream>>>(Wo, WoT, DM, DM, 0, 0);
    proj_mfma<<<dim3(16, 64), blk, 0, stream>>>(qb, WqT, bq, qsb, qscale, 0);
    proj_mfma<<<dim3(16, 64), blk, 0, stream>>>(kb, WkT, bk, khb, 1.0f, 1);
    proj_mfma<<<dim3(16, 64), blk, 0, stream>>>(vb, WvT, bv, vtb, 1.0f, 2);
    stats_mfma<<<dim3(16, 64), blk, 0, stream>>>(qsb, khb, izb);
    ctx_mfma<<<dim3(16, 64), blk, 0, stream>>>(qsb, khb, vtb, izb, ctc);
    out_mfma<<<dim3(128, 4), blk, 0, stream>>>(ctc, WoT, bo, out);
}

// Round 5
// 221.635 us; speedup vs baseline: 46.8732x; 1.0513x over previous
//
#include <hip/hip_runtime.h>
#include <hip/hip_bf16.h>
#include <math.h>

#define BB 8
#define SS 2048
#define HH 8
#define DM 512
#define DK 64

typedef short bf16x8 __attribute__((ext_vector_type(8)));
typedef float f32x4 __attribute__((ext_vector_type(4)));

static __device__ __forceinline__ short f2bf(float f) {
    union { __hip_bfloat16 h; short s; } u;
    u.h = __float2bfloat16(f);
    return u.s;
}

// exp2 (v_exp_f32); Q pre-scaled by 0.125*log2e so 2^s == e^(s/8)
static __device__ __forceinline__ float fexp2(float x) {
#if __has_builtin(__builtin_amdgcn_exp2f)
    return __builtin_amdgcn_exp2f(x);
#else
    return __expf(x * 0.69314718056f);
#endif
}

// async 16B global->LDS; LDS dest wave-uniform base + lane*16 implicit
static __device__ __forceinline__ void gld16(void* lds, const void* g) {
    __builtin_amdgcn_global_load_lds((const __attribute__((address_space(1))) void*)g,
                                     (__attribute__((address_space(3))) void*)lds, 16, 0, 0);
}

// swizzled read of 8 shorts from a [rows][64]-short LDS tile: 16B slot ^= (row&7)
static __device__ __forceinline__ bf16x8 fragRow(const short* lds, int row, int cshort) {
    return *(const bf16x8*)(lds + row * 64 + (cshort ^ ((row & 7) << 3)));
}

// raw barrier + scheduler fence (prevents ds_reads drifting across the barrier)
static __device__ __forceinline__ void bar() {
    __builtin_amdgcn_s_barrier();
    __builtin_amdgcn_sched_barrier(0);
}
#define WAITV4 asm volatile("s_waitcnt vmcnt(4)" ::: "memory")
#define WAITV2 asm volatile("s_waitcnt vmcnt(2)" ::: "memory")
#define WAITV0 asm volatile("s_waitcnt vmcnt(0)" ::: "memory")

// ---------------- transpose-convert: fp32 [R][C] -> bf16 [C][R] (per grid.z head) ----------------
__global__ __launch_bounds__(256) void tcvt(const float* __restrict__ src, short* __restrict__ dst,
                                            int R, int C, int srcHS, int dstHS) {
    __shared__ short T[64][72];
    src += (size_t)blockIdx.z * srcHS;
    dst += (size_t)blockIdx.z * dstHS;
    const int r0 = blockIdx.x * 64, c0 = blockIdx.y * 64;
    const int t = threadIdx.x;
#pragma unroll
    for (int p = 0; p < 4; ++p) {
        int idx = t + 256 * p;
        int row = idx >> 4, c4 = (idx & 15) * 4;
        float4 v = *(const float4*)(src + (size_t)(r0 + row) * C + c0 + c4);
        T[c4 + 0][row] = f2bf(v.x);
        T[c4 + 1][row] = f2bf(v.y);
        T[c4 + 2][row] = f2bf(v.z);
        T[c4 + 3][row] = f2bf(v.w);
    }
    __syncthreads();
#pragma unroll
    for (int p = 0; p < 2; ++p) {
        int idx = t + 256 * p;
        int row = idx >> 3, slot = idx & 7;
        *(bf16x8*)(dst + (size_t)(c0 + row) * R + r0 + slot * 8) = *(const bf16x8*)&T[row][slot * 8];
    }
}

// ---------------- projection: fp32 X (reg-staged+cvt) @ bf16 WT, bf16 MFMA ----------------
// mode 0/1: row-major [b,h,s,64] (scale applied); mode 2: V^T [b,h,64,s] k-permuted
__global__ __launch_bounds__(256, 3) void proj_mfma(const float* __restrict__ X,
                                                    const short* __restrict__ WT,
                                                    const float* __restrict__ bias,
                                                    short* __restrict__ Y, float scale, int mode) {
    __shared__ short As[2][128 * 64];
    __shared__ short Bs[2][64 * 64];
    const int lin = blockIdx.x;
    const int b = lin & 7, h = (lin >> 3) & 7;      // same-b blocks share an XCD's L2
    const int s0 = (lin >> 6) * 128;
    const int bh = b * 8 + h;
    const int t = threadIdx.x;
    const int l = t & 63, w = t >> 6;
    const int lr = l & 15, g = l >> 4;
    const float* Xb = X + ((size_t)b * SS + s0) * DM;
    const short* Wh = WT + (size_t)h * DK * DM;
    f32x4 acc[2][4];
#pragma unroll
    for (int i = 0; i < 2; ++i)
#pragma unroll
        for (int j = 0; j < 4; ++j) acc[i][j] = (f32x4){0.f, 0.f, 0.f, 0.f};

    float4 ra[8];
    auto loadA = [&](int k0) {
#pragma unroll
        for (int p = 0; p < 4; ++p) {
            int c = p * 256 + t;
            int row = c >> 3, col = (c & 7) * 8;
            ra[2 * p]     = *(const float4*)(Xb + (size_t)row * DM + k0 + col);
            ra[2 * p + 1] = *(const float4*)(Xb + (size_t)row * DM + k0 + col + 4);
        }
    };
    auto writeA = [&](int buf) {
#pragma unroll
        for (int p = 0; p < 4; ++p) {
            int c = p * 256 + t;
            int row = c >> 3, slot = c & 7;
            bf16x8 o;
            o[0] = f2bf(ra[2 * p].x); o[1] = f2bf(ra[2 * p].y);
            o[2] = f2bf(ra[2 * p].z); o[3] = f2bf(ra[2 * p].w);
            o[4] = f2bf(ra[2 * p + 1].x); o[5] = f2bf(ra[2 * p + 1].y);
            o[6] = f2bf(ra[2 * p + 1].z); o[7] = f2bf(ra[2 * p + 1].w);
            *(bf16x8*)(As[buf] + row * 64 + ((slot ^ (row & 7)) * 8)) = o;
        }
    };
    auto stageB = [&](int buf, int k0) {
#pragma unroll
        for (int p = 0; p < 2; ++p) {
            int c = p * 256 + w * 64 + l;
            int row = c >> 3, slot = c & 7;
            gld16(Bs[buf] + (size_t)(p * 256 + w * 64) * 8,
                  Wh + (size_t)row * DM + k0 + ((slot ^ (row & 7)) * 8));
        }
    };

    loadA(0);
    stageB(0, 0);
    writeA(0);                    // compiler inserts waits for ra
    __syncthreads();
    int cur = 0;
    for (int k0 = 0; k0 < DM; k0 += 64) {
        const bool next = (k0 + 64 < DM);
        if (next) { loadA(k0 + 64); stageB(cur ^ 1, k0 + 64); }
        bf16x8 bfr[4][2];
#pragma unroll
        for (int bf = 0; bf < 4; ++bf) {
            bfr[bf][0] = fragRow(Bs[cur], 16 * bf + lr, 8 * g);
            bfr[bf][1] = fragRow(Bs[cur], 16 * bf + lr, 32 + 8 * g);
        }
#pragma unroll
        for (int af = 0; af < 2; ++af) {
            bf16x8 a0 = fragRow(As[cur], 32 * w + 16 * af + lr, 8 * g);
            bf16x8 a1 = fragRow(As[cur], 32 * w + 16 * af + lr, 32 + 8 * g);
#pragma unroll
            for (int bf = 0; bf < 4; ++bf) {
                acc[af][bf] = __builtin_amdgcn_mfma_f32_16x16x32_bf16(a0, bfr[bf][0], acc[af][bf], 0, 0, 0);
                acc[af][bf] = __builtin_amdgcn_mfma_f32_16x16x32_bf16(a1, bfr[bf][1], acc[af][bf], 0, 0, 0);
            }
        }
        if (next) writeA(cur ^ 1);
        __syncthreads();
        cur ^= 1;
    }
    if (mode == 2) {
        // V^T with within-32 k-permutation: offset 16qf+4g+r stored at 8g+4qf+r
        short* Yb = Y + (size_t)bh * DK * SS;
#pragma unroll
        for (int qf = 0; qf < 2; ++qf)
#pragma unroll
            for (int nf = 0; nf < 4; ++nf) {
                int n = 16 * nf + lr;
                float bv = bias[h * DK + n];
                short4 o;
                o.x = f2bf(acc[qf][nf][0] + bv);
                o.y = f2bf(acc[qf][nf][1] + bv);
                o.z = f2bf(acc[qf][nf][2] + bv);
                o.w = f2bf(acc[qf][nf][3] + bv);
                *(short4*)(Yb + (size_t)n * SS + s0 + 32 * w + 8 * g + 4 * qf) = o;
            }
    } else {
        short* Yb = Y + ((size_t)bh * SS + s0) * DK;
#pragma unroll
        for (int qf = 0; qf < 2; ++qf)
#pragma unroll
            for (int nf = 0; nf < 4; ++nf) {
                int n = 16 * nf + lr;
                float bv = bias[h * DK + n];
#pragma unroll
                for (int r = 0; r < 4; ++r)
                    Yb[(size_t)(32 * w + 16 * qf + 4 * g + r) * DK + n] =
                        f2bf((acc[qf][nf][r] + bv) * scale);
            }
    }
}

// ---------------- stats: z[k] = sum_q 2^s'; k-tile 256/block, 64 k-cols/wave ----------------
__global__ __launch_bounds__(256, 2) void stats_mfma(const short* __restrict__ qs,
                                                     const short* __restrict__ kh,
                                                     float* __restrict__ izOut) {
    __shared__ short Ks[256 * 64];     // 32 KB, staged once
    __shared__ short Qs[3][64 * 64];   // 24 KB, depth-2 prefetch
    const int bid = blockIdx.x;
    const int r = bid & 63;
    const int bh = ((r & 7) << 3) | (r >> 3);   // same-bh blocks share an XCD
    const int k0 = (bid >> 6) * 256;
    const int t = threadIdx.x;
    const int l = t & 63, w = t >> 6;
    const int lr = l & 15, g = l >> 4;
    const short* Qb = qs + (size_t)bh * SS * DK;
    const short* Kb = kh + ((size_t)bh * SS + k0) * DK;

#pragma unroll
    for (int p = 0; p < 8; ++p) {
        int c = p * 256 + w * 64 + l;
        int row = c >> 3, slot = c & 7;
        gld16(Ks + (size_t)(p * 256 + w * 64) * 8,
              Kb + (size_t)row * DK + ((slot ^ (row & 7)) * 8));
    }
    auto stageQ = [&](int buf, int qq) {
#pragma unroll
        for (int p = 0; p < 2; ++p) {
            int c = p * 256 + w * 64 + l;
            int row = c >> 3, slot = c & 7;
            gld16(Qs[buf] + (size_t)(p * 256 + w * 64) * 8,
                  Qb + (size_t)(qq + row) * DK + ((slot ^ (row & 7)) * 8));
        }
    };
    stageQ(0, 0);
    stageQ(1, 64);
    WAITV2;          // Ks + Q0 landed; Q1 in flight
    bar();

    bf16x8 bk[4][2]; // wave's 64 k-cols
#pragma unroll
    for (int c2 = 0; c2 < 4; ++c2) {
        bk[c2][0] = fragRow(Ks, 64 * w + 16 * c2 + lr, 8 * g);
        bk[c2][1] = fragRow(Ks, 64 * w + 16 * c2 + lr, 32 + 8 * g);
    }
    f32x4 zacc[4];
#pragma unroll
    for (int c2 = 0; c2 < 4; ++c2) zacc[c2] = (f32x4){0.f, 0.f, 0.f, 0.f};

    int cur = 0;
    for (int it = 0; it < 32; ++it) {
        const bool pre = (it < 30);
        if (pre) {
            int nb = cur + 2; if (nb >= 3) nb -= 3;
            stageQ(nb, (it + 2) * 64);
        }
#pragma unroll
        for (int qf = 0; qf < 4; ++qf) {
            bf16x8 aq0 = fragRow(Qs[cur], 16 * qf + lr, 8 * g);
            bf16x8 aq1 = fragRow(Qs[cur], 16 * qf + lr, 32 + 8 * g);
#pragma unroll
            for (int c2 = 0; c2 < 4; ++c2) {
                f32x4 s = {0.f, 0.f, 0.f, 0.f};
                s = __builtin_amdgcn_mfma_f32_16x16x32_bf16(aq0, bk[c2][0], s, 0, 0, 0);
                s = __builtin_amdgcn_mfma_f32_16x16x32_bf16(aq1, bk[c2][1], s, 0, 0, 0);
#pragma unroll
                for (int rr = 0; rr < 4; ++rr)
                    zacc[c2][rr] += fexp2(s[rr]);
            }
        }
        if (pre) { WAITV2; } else { WAITV0; }
        bar();
        cur = (cur == 2) ? 0 : cur + 1;
    }
#pragma unroll
    for (int c2 = 0; c2 < 4; ++c2) {
        float z = zacc[c2][0] + zacc[c2][1] + zacc[c2][2] + zacc[c2][3];
        z += __shfl_xor(z, 16);
        z += __shfl_xor(z, 32);
        if (l < 16)
            izOut[(size_t)bh * SS + k0 + 64 * w + 16 * c2 + l] = 1.f / z;
    }
}

// ---------------- ctx: q-tile 256 (64 q/wave), depth-2 counted-vmcnt pipeline ----------------
__global__ __launch_bounds__(256, 2) void ctx_mfma(const short* __restrict__ qs,
                                                   const short* __restrict__ kh,
                                                   const short* __restrict__ vP,
                                                   const float* __restrict__ izArr,
                                                   short* __restrict__ ctxc) {
    __shared__ short Qs[256 * 64];     // 32 KB
    __shared__ short Ks[3][64 * 64];   // 24 KB
    __shared__ short Vs[3][64 * 64];   // 24 KB
    const int bid = blockIdx.x;
    const int r = bid & 63;
    const int bh = ((r & 7) << 3) | (r >> 3);
    const int q0 = (bid >> 6) * 256;
    const int b = bh >> 3, h = bh & 7;
    const int t = threadIdx.x;
    const int l = t & 63, w = t >> 6;
    const int lr = l & 15, g = l >> 4;
    const short* Qb = qs + ((size_t)bh * SS + q0) * DK;
    const short* Kb = kh + (size_t)bh * SS * DK;
    const short* Vb = vP + (size_t)bh * DK * SS;
    const float* zB = izArr + (size_t)bh * SS;

#pragma unroll
    for (int p = 0; p < 8; ++p) {
        int c = p * 256 + w * 64 + l;
        int row = c >> 3, slot = c & 7;
        gld16(Qs + (size_t)(p * 256 + w * 64) * 8,
              Qb + (size_t)row * DK + ((slot ^ (row & 7)) * 8));
    }
    auto stageKV = [&](int buf, int kk) {
#pragma unroll
        for (int p = 0; p < 2; ++p) {
            int c = p * 256 + w * 64 + l;
            int row = c >> 3, slot = c & 7;
            gld16(Ks[buf] + (size_t)(p * 256 + w * 64) * 8,
                  Kb + (size_t)(kk + row) * DK + ((slot ^ (row & 7)) * 8));
        }
#pragma unroll
        for (int p = 0; p < 2; ++p) {
            int c = p * 256 + w * 64 + l;
            int row = c >> 3, slot = c & 7;
            gld16(Vs[buf] + (size_t)(p * 256 + w * 64) * 8,
                  Vb + (size_t)row * SS + kk + ((slot ^ (row & 7)) * 8));
        }
    };
    stageKV(0, 0);
    stageKV(1, 64);
    WAITV4;          // Q + KV0 landed; KV1 in flight
    bar();

    bf16x8 qfr[4][2];  // wave's 64 q-cols hoisted
#pragma unroll
    for (int qf = 0; qf < 4; ++qf)
#pragma unroll
        for (int c = 0; c < 2; ++c)
            qfr[qf][c] = fragRow(Qs, 64 * w + 16 * qf + lr, 32 * c + 8 * g);

    f32x4 acc[4][4];
#pragma unroll
    for (int a = 0; a < 4; ++a)
#pragma unroll
        for (int b2 = 0; b2 < 4; ++b2) acc[a][b2] = (f32x4){0.f, 0.f, 0.f, 0.f};

    int cur = 0;
    for (int it = 0; it < 32; ++it) {
        const int k0 = it * 64;
        const bool pre = (it < 30);
        f32x4 z4[4];
#pragma unroll
        for (int kf = 0; kf < 4; ++kf)
            z4[kf] = *(const f32x4*)(zB + k0 + 16 * kf + 4 * g);
        __builtin_amdgcn_sched_barrier(0);   // z-loads stay before stage gld16s
        if (pre) {
            int nb = cur + 2; if (nb >= 3) nb -= 3;
            stageKV(nb, k0 + 128);
        }
        // K frags for this tile (read once per iter)
        bf16x8 Kf[4][2];
#pragma unroll
        for (int kf = 0; kf < 4; ++kf) {
            Kf[kf][0] = fragRow(Ks[cur], 16 * kf + lr, 8 * g);
            Kf[kf][1] = fragRow(Ks[cur], 16 * kf + lr, 32 + 8 * g);
        }
        // S phase per qf: swapped mfma(K,Q) -> lane owns k=16kf+4g+rr for q=64w+16qf+lr
        bf16x8 pa[4][2];
#pragma unroll
        for (int qf = 0; qf < 4; ++qf) {
            float pw[4][4];
#pragma unroll
            for (int kf = 0; kf < 4; ++kf) {
                f32x4 s = {0.f, 0.f, 0.f, 0.f};
                s = __builtin_amdgcn_mfma_f32_16x16x32_bf16(Kf[kf][0], qfr[qf][0], s, 0, 0, 0);
                s = __builtin_amdgcn_mfma_f32_16x16x32_bf16(Kf[kf][1], qfr[qf][1], s, 0, 0, 0);
#pragma unroll
                for (int rr = 0; rr < 4; ++rr)
                    pw[kf][rr] = fexp2(s[rr]) * z4[kf][rr];
            }
#pragma unroll
            for (int c = 0; c < 2; ++c)
#pragma unroll
                for (int e = 0; e < 4; ++e) {
                    pa[qf][c][e]     = f2bf(pw[2 * c][e]);
                    pa[qf][c][4 + e] = f2bf(pw[2 * c + 1][e]);
                }
        }
        // PV: V pre-permuted -> standard swizzled frag read; V read once per iter
#pragma unroll
        for (int vf = 0; vf < 4; ++vf)
#pragma unroll
            for (int c = 0; c < 2; ++c) {
                bf16x8 bv = fragRow(Vs[cur], 16 * vf + lr, 32 * c + 8 * g);
#pragma unroll
                for (int qf = 0; qf < 4; ++qf)
                    acc[qf][vf] = __builtin_amdgcn_mfma_f32_16x16x32_bf16(pa[qf][c], bv, acc[qf][vf], 0, 0, 0);
            }
        if (pre) { WAITV4; } else { WAITV0; }
        bar();
        cur = (cur == 2) ? 0 : cur + 1;
    }
    // bf16 concat-layout write [b, s, h*64+v]
    short* Cb = ctxc + ((size_t)b * SS + q0) * (HH * DK) + h * DK;
#pragma unroll
    for (int qf = 0; qf < 4; ++qf)
#pragma unroll
        for (int vf = 0; vf < 4; ++vf)
#pragma unroll
            for (int rr = 0; rr < 4; ++rr)
                Cb[(size_t)(64 * w + 16 * qf + 4 * g + rr) * (HH * DK) + 16 * vf + lr] =
                    f2bf(acc[qf][vf][rr]);
}

// ---------------- output projection: [16384x512]bf16 @ WoT + bo -> fp32, 2-phase ----------------
__global__ __launch_bounds__(256) void out_mfma(const short* __restrict__ A,
                                                const short* __restrict__ BT,
                                                const float* __restrict__ bo,
                                                float* __restrict__ out) {
    __shared__ short As[2][128 * 64];
    __shared__ short Bs[2][128 * 64];
    const int r0 = blockIdx.x * 128;
    const int j0 = blockIdx.y * 128;
    const int t = threadIdx.x;
    const int l = t & 63, w = t >> 6;
    const int lr = l & 15, g = l >> 4;
    const int wr = w >> 1, wc = w & 1;
    f32x4 acc[4][4];
#pragma unroll
    for (int i = 0; i < 4; ++i)
#pragma unroll
        for (int j = 0; j < 4; ++j) acc[i][j] = (f32x4){0.f, 0.f, 0.f, 0.f};

    auto stage = [&](int buf, int k0) {
#pragma unroll
        for (int p = 0; p < 4; ++p) {
            int c = p * 256 + w * 64 + l;
            int row = c >> 3, slot = c & 7;
            gld16(As[buf] + (size_t)(p * 256 + w * 64) * 8,
                  A + (size_t)(r0 + row) * DM + k0 + ((slot ^ (row & 7)) * 8));
            gld16(Bs[buf] + (size_t)(p * 256 + w * 64) * 8,
                  BT + (size_t)(j0 + row) * DM + k0 + ((slot ^ (row & 7)) * 8));
        }
    };
    stage(0, 0);
    WAITV0;
    __syncthreads();
    int cur = 0;
    for (int k0 = 0; k0 < DM; k0 += 64) {
        if (k0 + 64 < DM) stage(cur ^ 1, k0 + 64);
        bf16x8 bfr[4][2];
#pragma unroll
        for (int bf = 0; bf < 4; ++bf) {
            bfr[bf][0] = fragRow(Bs[cur], 64 * wc + 16 * bf + lr, 8 * g);
            bfr[bf][1] = fragRow(Bs[cur], 64 * wc + 16 * bf + lr, 32 + 8 * g);
        }
#pragma unroll
        for (int af = 0; af < 4; ++af) {
            bf16x8 a0 = fragRow(As[cur], 64 * wr + 16 * af + lr, 8 * g);
            bf16x8 a1 = fragRow(As[cur], 64 * wr + 16 * af + lr, 32 + 8 * g);
#pragma unroll
            for (int bf = 0; bf < 4; ++bf) {
                acc[af][bf] = __builtin_amdgcn_mfma_f32_16x16x32_bf16(a0, bfr[bf][0], acc[af][bf], 0, 0, 0);
                acc[af][bf] = __builtin_amdgcn_mfma_f32_16x16x32_bf16(a1, bfr[bf][1], acc[af][bf], 0, 0, 0);
            }
        }
        __syncthreads();
        cur ^= 1;
    }
#pragma unroll
    for (int af = 0; af < 4; ++af)
#pragma unroll
        for (int bf = 0; bf < 4; ++bf) {
            int j = j0 + 64 * wc + 16 * bf + lr;
            float bv = bo[j];
#pragma unroll
            for (int rr = 0; rr < 4; ++rr)
                out[(size_t)(r0 + 64 * wr + 16 * af + 4 * g + rr) * DM + j] = acc[af][bf][rr] + bv;
        }
}

extern "C" void kernel_launch(void* const* d_in, const int* in_sizes, int n_in,
                              void* d_out, int out_size, void* d_ws, size_t ws_size,
                              hipStream_t stream) {
    const float* q  = (const float*)d_in[0];
    const float* k  = (const float*)d_in[1];
    const float* v  = (const float*)d_in[2];
    const float* Wq = (const float*)d_in[3];
    const float* bq = (const float*)d_in[4];
    const float* Wk = (const float*)d_in[5];
    const float* bk = (const float*)d_in[6];
    const float* Wv = (const float*)d_in[7];
    const float* bv = (const float*)d_in[8];
    const float* Wo = (const float*)d_in[9];
    const float* bo = (const float*)d_in[10];
    float* out = (float*)d_out;

    short* w16 = (short*)d_ws;
    const size_t NH = (size_t)BB * HH * SS * DK;  // 8,388,608
    const size_t NW = (size_t)HH * DM * DK;       // 262,144
    short* WqT = w16;
    short* WkT = WqT + NW;
    short* WvT = WkT + NW;
    short* WoT = WvT + NW;
    short* qsb = WoT + NW;
    short* khb = qsb + NH;
    short* vtb = khb + NH;
    short* ctc = vtb + NH;
    float* izb = (float*)(ctc + NH);

    const float qscale = 0.125f * 1.4426950408889634f;   // fold 1/sqrt(dk) and log2e

    dim3 blk(256);
    tcvt<<<dim3(8, 1, 8), blk, 0, stream>>>(Wq, WqT, DM, DK, DM * DK, DK * DM);
    tcvt<<<dim3(8, 1, 8), blk, 0, stream>>>(Wk, WkT, DM, DK, DM * DK, DK * DM);
    tcvt<<<dim3(8, 1, 8), blk, 0, stream>>>(Wv, WvT, DM, DK, DM * DK, DK * DM);
    tcvt<<<dim3(8, 8, 1), blk, 0, stream>>>(Wo, WoT, DM, DM, 0, 0);
    proj_mfma<<<dim3(1024), blk, 0, stream>>>(q, WqT, bq, qsb, qscale, 0);
    proj_mfma<<<dim3(1024), blk, 0, stream>>>(k, WkT, bk, khb, 1.0f, 1);
    proj_mfma<<<dim3(1024), blk, 0, stream>>>(v, WvT, bv, vtb, 1.0f, 2);
    stats_mfma<<<dim3(512), blk, 0, stream>>>(qsb, khb, izb);
    ctx_mfma<<<dim3(512), blk, 0, stream>>>(qsb, khb, vtb, izb, ctc);
    out_mfma<<<dim3(128, 4), blk, 0, stream>>>(ctc, WoT, bo, out);
}